// Round 8
// baseline (3552.375 us; speedup 1.0000x reference)
//
#include <hip/hip_runtime.h>
#include <hip/hip_bf16.h>
#include <math.h>

#define N_PTS 15872
#define M_PTS 35637
#define KNN_K 5
#define KUP   20
#define UP_ROWS (M_PTS * KUP)   // 712740
#define NTILE (N_PTS/32)        // 496 i/j tiles
#define CDIV(a,b) (((a)+(b)-1)/(b))

typedef __hip_bfloat16 bf16;
typedef unsigned int uint;
typedef unsigned short ushort_t;
__device__ __forceinline__ float b2f(bf16 x){ return __bfloat162float(x); }

// round-to-nearest-even fp32 -> bf16 bit pattern (finite inputs)
__device__ __forceinline__ uint f2bf_bits(float x){
  uint u = __float_as_uint(x);
  return (u + 0x7FFFu + ((u>>16)&1u)) >> 16;
}

typedef __attribute__((ext_vector_type(8))) short bf16x8;
typedef __attribute__((ext_vector_type(16))) float f32x16;
union FragAB { bf16x8 v; uint u[4]; };
union FragB  { bf16x8 v; uint4 q; };
union Acc16  { f32x16 v; float f[16]; };

// ---------------------------------------------------------------------------
__global__ void flag_k(const uint* __restrict__ pos_raw, int* __restrict__ flag){
  if (threadIdx.x == 0 && blockIdx.x == 0)
    flag[0] = (pos_raw[0] == 0x3F800000u) ? 1 : 0;
}

struct CvtTab { const void* src[52]; int start[52]; };
__global__ __launch_bounds__(256) void cvt_all_k(CvtTab tab, float* __restrict__ dst,
                                                 const int* __restrict__ flag, int total){
  int i = blockIdx.x*256 + threadIdx.x;
  if (i >= total) return;
  int s = 0;
#pragma unroll 1
  for (int k = 1; k < 52; k++) if (tab.start[k] <= i) s = k;
  int off = i - tab.start[s];
  float v = flag[0] ? b2f(((const bf16*)tab.src[s])[off]) : ((const float*)tab.src[s])[off];
  dst[i] = v;
}

// pack SIREN 128x128 weights into frag-major split-bf16 hi/lo planes.
__global__ void packfrag_k(const float* __restrict__ w, ushort_t* __restrict__ whi,
                           ushort_t* __restrict__ wlo, int n){
  int i = blockIdx.x*256 + threadIdx.x;
  if (i >= n) return;
  int j = i & 7;
  int lam = (i >> 3) & 63;
  int fg = i >> 9;
  int t = fg & 3, ks = (fg >> 2) & 1, Q = (fg >> 3) & 3, l = fg >> 5;
  int nn = t*32 + (lam & 31);
  int kk = Q*32 + ks*16 + (lam >> 5)*8 + j;
  float x = w[l*16384 + nn*128 + kk];
  uint hb = f2bf_bits(x);
  uint lb = f2bf_bits(x - __uint_as_float(hb << 16));
  whi[i] = (ushort_t)hb;
  wlo[i] = (ushort_t)lb;
}

// generic frag-major split-bf16 pack for a weight matrix W[N][K] (row-major),
// K padded to Kpad (x32), N padded to x32 with zeros.
// slot i: j=i&7, lane=(i>>3)&63, fr=i>>9: ks=fr&1, q=(fr>>1)%nq, nt=(fr>>1)/nq
__global__ void packw_mfma_k(const float* __restrict__ w, ushort_t* __restrict__ whi,
                             ushort_t* __restrict__ wlo, int N, int K, int Kpad, int total){
  int i = blockIdx.x*256 + threadIdx.x;
  if (i >= total) return;
  int j = i & 7;
  int lane = (i >> 3) & 63;
  int fr = i >> 9;
  int nq = Kpad >> 5;
  int ks = fr & 1;
  int q  = (fr >> 1) % nq;
  int nt = (fr >> 1) / nq;
  int n = nt*32 + (lane & 31);
  int k = q*32 + ks*16 + (lane >> 5)*8 + j;
  float x = (n < N && k < K) ? w[(size_t)n*K + k] : 0.f;
  uint hb = f2bf_bits(x);
  uint lb = f2bf_bits(x - __uint_as_float(hb << 16));
  whi[i] = (ushort_t)hb;
  wlo[i] = (ushort_t)lb;
}

// pack KNN features into frag-major split-bf16 planes with norm augmentation.
__global__ void packknn_k(const float* __restrict__ xf, const float* __restrict__ nr,
                          ushort_t* __restrict__ ahi, ushort_t* __restrict__ alo,
                          ushort_t* __restrict__ bhi, ushort_t* __restrict__ blo){
  int i = blockIdx.x*256 + threadIdx.x;
  if (i >= NTILE*5*64*8) return;
  int e = i & 7;
  int lane = (i >> 3) & 63;
  int rest = i >> 9;
  int kc = rest % 5, jt = rest / 5;
  int n = jt*32 + (lane & 31);
  int k = kc*16 + (lane >> 5)*8 + e;
  float f = (k < 64) ? xf[(size_t)n*227 + 35 + k] : 0.f;
  float av, bv;
  if (k < 64)      { av = 2.f*f;   bv = f; }
  else if (k == 64){ av = nr[n];   bv = -1.f; }
  else if (k == 65){ av = 1.f;     bv = -nr[n]; }
  else             { av = 0.f;     bv = 0.f; }
  uint ah = f2bf_bits(av); uint al = f2bf_bits(av - __uint_as_float(ah<<16));
  uint bh = f2bf_bits(bv); uint bl = f2bf_bits(bv - __uint_as_float(bh<<16));
  ahi[i] = (ushort_t)ah; alo[i] = (ushort_t)al;
  bhi[i] = (ushort_t)bh; blo[i] = (ushort_t)bl;
}

__global__ void fillmark_k(bf16* __restrict__ out, int n){
  int i = blockIdx.x*256 + threadIdx.x;
  if (i < n) out[i] = __float2bfloat16(12345.0f);
}

// ---------------------------------------------------------------------------
// Generic split-bf16 MFMA GEMM: C[m,n] = ACT(EPI(sum_k A[m,k]*W[n,k]))
// A fp32 (staged to LDS pre-split hi/lo pair-packed), W from frag-major planes.
// Block 256 = 4 waves; tile 128 rows x 128 cols; grid (CDIV(M,128), CDIV(N,128)).
// EPI 0: v*scale+shift  1: v+shift  2: (v+shift)*gmul ; ACT 0 none 1 lrelu 2 sin
// ---------------------------------------------------------------------------
template<int EPI, int ACT>
__global__ __launch_bounds__(256) void gemm_mfma_k(
    const float* __restrict__ A, int lda, int M, int K,
    const ushort_t* __restrict__ whi, const ushort_t* __restrict__ wlo, int Kpad,
    const float* __restrict__ scale, const float* __restrict__ shift, float gmul,
    float* __restrict__ C, int ldc, int Nout)
{
  __shared__ __align__(16) uint AH[8*64*4];   // [w][ks][lane][p] hi pair-packed
  __shared__ __align__(16) uint AL[8*64*4];
  const int tid = threadIdx.x;
  const int lane = tid & 63;
  const int wv = tid >> 6;
  const int np = lane & 31;
  const int hb2 = lane >> 5;
  const int bm = blockIdx.x * 128;
  const int bn = blockIdx.y * 128;
  const int nq = Kpad >> 5;
  int ntiles = (Nout - bn + 31) >> 5; if (ntiles > 4) ntiles = 4;

  Acc16 acc[4];
#pragma unroll
  for (int t=0;t<4;t++)
#pragma unroll
    for (int i=0;i<16;i++) acc[t].f[i] = 0.f;

#pragma unroll 1
  for (int q = 0; q < nq; q++){
    __syncthreads();
    int k0 = q*32;
#pragma unroll
    for (int s = 0; s < 8; s++){
      int slot = tid + s*256;
      int row = slot >> 4, kp = slot & 15;
      int rowg = bm + row;
      int k = k0 + kp*2;
      float f0 = (rowg < M && k   < K) ? A[(size_t)rowg*lda + k]   : 0.f;
      float f1 = (rowg < M && k+1 < K) ? A[(size_t)rowg*lda + k+1] : 0.f;
      uint h0 = f2bf_bits(f0); uint l0 = f2bf_bits(f0 - __uint_as_float(h0<<16));
      uint h1 = f2bf_bits(f1); uint l1 = f2bf_bits(f1 - __uint_as_float(h1<<16));
      int w = row >> 5, rnp = row & 31;
      int kl = kp*2;
      int ks = kl >> 4, r = kl & 15;
      int h2 = r >> 3, p = (r & 7) >> 1;
      int addr = ((w*2 + ks)*64 + (rnp + 32*h2))*4 + p;
      AH[addr] = h0 | (h1<<16);
      AL[addr] = l0 | (l1<<16);
    }
    __syncthreads();
#pragma unroll
    for (int ks = 0; ks < 2; ks++){
      FragB ah, al;
      ah.q = *(const uint4*)&AH[((wv*2+ks)*64 + lane)*4];
      al.q = *(const uint4*)&AL[((wv*2+ks)*64 + lane)*4];
#pragma unroll
      for (int t = 0; t < 4; t++){
        if (t < ntiles){
          int ntg = (bn>>5) + t;
          size_t fb = ((size_t)((ntg*nq + q)*2 + ks))*512 + (size_t)lane*8;
          FragB bh, bl;
          bh.q = *(const uint4*)(whi + fb);
          bl.q = *(const uint4*)(wlo + fb);
          acc[t].v = __builtin_amdgcn_mfma_f32_32x32x16_bf16(ah.v, bh.v, acc[t].v, 0,0,0);
          acc[t].v = __builtin_amdgcn_mfma_f32_32x32x16_bf16(al.v, bh.v, acc[t].v, 0,0,0);
          acc[t].v = __builtin_amdgcn_mfma_f32_32x32x16_bf16(ah.v, bl.v, acc[t].v, 0,0,0);
        }
      }
    }
  }
#pragma unroll
  for (int t = 0; t < 4; t++){
    if (t < ntiles){
      int col = bn + t*32 + np;
      if (col < Nout){
        float scv = (EPI==0) ? scale[col] : 0.f;
        float shv = shift[col];
#pragma unroll
        for (int reg = 0; reg < 16; reg++){
          int row = bm + wv*32 + (reg&3) + 8*(reg>>2) + 4*hb2;
          if (row < M){
            float v = acc[t].f[reg];
            if (EPI==0)      v = v*scv + shv;
            else if (EPI==1) v = v + shv;
            else             v = (v + shv)*gmul;
            if (ACT==1)      v = v > 0.f ? v : 0.2f*v;
            else if (ACT==2) v = __sinf(v);
            C[(size_t)row*ldc + col] = v;
          }
        }
      }
    }
  }
}

// ---------------------------------------------------------------------------
// MFMA KNN (validated round 7).
// ---------------------------------------------------------------------------
#define INS5(tv, tj, v, j) \
  if ((v) > tv[4]){ tv[4]=(v); tj[4]=(j); \
    _Pragma("unroll") \
    for (int q=4;q>0;q--) \
      if (tv[q] > tv[q-1]){ float tf=tv[q-1]; tv[q-1]=tv[q]; tv[q]=tf; \
                            int ti=tj[q-1]; tj[q-1]=tj[q]; tj[q]=ti; } }

__global__ __launch_bounds__(256) void knn_mfma_k(
    const ushort_t* __restrict__ ahi, const ushort_t* __restrict__ alo,
    const ushort_t* __restrict__ bhi, const ushort_t* __restrict__ blo,
    int* __restrict__ out)
{
  __shared__ float mv[4][32][5];
  __shared__ int   mjj[4][32][5];
  const int tid = threadIdx.x;
  const int lane = tid & 63;
  const int wv = tid >> 6;
  const int np = lane & 31;
  const int hb2 = lane >> 5;
  const int it = blockIdx.x;
  const int ig = it*32 + np;

  FragB vh[5], vl[5];
  {
    size_t bb = (size_t)(it*5)*512 + (size_t)lane*8;
#pragma unroll
    for (int kc=0;kc<5;kc++){
      vh[kc].q = *(const uint4*)(bhi + bb + kc*512);
      vl[kc].q = *(const uint4*)(blo + bb + kc*512);
    }
  }

  float tv[5] = {-1e30f,-1e30f,-1e30f,-1e30f,-1e30f};
  int   tj[5] = {0,0,0,0,0};

  FragB uh[5], ul[5], nh[5], nl[5];
  {
    size_t ab = (size_t)(wv*5)*512 + (size_t)lane*8;
#pragma unroll
    for (int kc=0;kc<5;kc++){
      uh[kc].q = *(const uint4*)(ahi + ab + kc*512);
      ul[kc].q = *(const uint4*)(alo + ab + kc*512);
    }
  }

#pragma unroll 1
  for (int t = 0; t < NTILE/4; t++){
    int jt = wv + t*4;
    if (t+1 < NTILE/4){
      size_t an = (size_t)((jt+4)*5)*512 + (size_t)lane*8;
#pragma unroll
      for (int kc=0;kc<5;kc++){
        nh[kc].q = *(const uint4*)(ahi + an + kc*512);
        nl[kc].q = *(const uint4*)(alo + an + kc*512);
      }
    }
    Acc16 acc;
#pragma unroll
    for (int q=0;q<16;q++) acc.f[q] = 0.f;
#pragma unroll
    for (int kc=0;kc<5;kc++){
      acc.v = __builtin_amdgcn_mfma_f32_32x32x16_bf16(uh[kc].v, vh[kc].v, acc.v, 0,0,0);
      acc.v = __builtin_amdgcn_mfma_f32_32x32x16_bf16(ul[kc].v, vh[kc].v, acc.v, 0,0,0);
      acc.v = __builtin_amdgcn_mfma_f32_32x32x16_bf16(uh[kc].v, vl[kc].v, acc.v, 0,0,0);
    }
    int jb = jt*32 + 4*hb2;
#pragma unroll
    for (int reg=0;reg<16;reg++){
      int j = jb + (reg&3) + 8*(reg>>2);
      float v = acc.f[reg];
      if (j != ig) { INS5(tv, tj, v, j); }
    }
    if (t+1 < NTILE/4){
#pragma unroll
      for (int kc=0;kc<5;kc++){ uh[kc] = nh[kc]; ul[kc] = nl[kc]; }
    }
  }

#pragma unroll
  for (int s=0;s<5;s++){
    float ov = __shfl_xor(tv[s], 32, 64);
    int   oj = __shfl_xor(tj[s], 32, 64);
    INS5(tv, tj, ov, oj);
  }
  if (hb2 == 0){
#pragma unroll
    for (int s=0;s<5;s++){ mv[wv][np][s] = tv[s]; mjj[wv][np][s] = tj[s]; }
  }
  __syncthreads();
  if (tid < 32){
    float bv[5]; int bj[5];
#pragma unroll
    for (int s=0;s<5;s++){ bv[s] = mv[0][tid][s]; bj[s] = mjj[0][tid][s]; }
#pragma unroll
    for (int w=1;w<4;w++)
#pragma unroll
      for (int s=0;s<5;s++){
        float v = mv[w][tid][s]; int j = mjj[w][tid][s];
        INS5(bv, bj, v, j);
      }
    int gi = it*32 + tid;
#pragma unroll
    for (int s=0;s<5;s++) out[gi*KNN_K + s] = bj[s];
  }
}

// ---------------------------------------------------------------------------
// Fused 8-layer SIREN + head (validated round 5/7).
// ---------------------------------------------------------------------------
__global__ __launch_bounds__(256, 2) void siren_fused_k(
    const void* __restrict__ upin,
    const ushort_t* __restrict__ whi, const ushort_t* __restrict__ wlo,
    const float* __restrict__ W0c, const float* __restrict__ S0c, const float* __restrict__ H0c,
    const float* __restrict__ SRc, const float* __restrict__ HRc,
    const float* __restrict__ WFc, const float* __restrict__ BFc,
    float* __restrict__ logits, const int* __restrict__ flag)
{
  __shared__ __align__(16) uint act[4*32*128];
  __shared__ float intile[4*32*8];
  __shared__ float w0s[128*9];
  __shared__ float wfs[128];
  __shared__ float bfs[1];

  const int tid  = threadIdx.x;
  const int lane = tid & 63;
  const int wv   = tid >> 6;
  const int np   = lane & 31;
  const int hb2  = lane >> 5;
  const int rowbase = blockIdx.x * 128 + wv * 32;
  const int isbf = flag[0];
  uint*  actw = act + wv*32*128;
  float* intw = intile + wv*32*8;

  for (int e = tid; e < 128*7; e += 256) w0s[(e/7)*9 + (e%7)] = W0c[e];
  if (tid < 128) wfs[tid] = WFc[tid];
  if (tid == 0) bfs[0] = BFc[0];
  for (int e = lane; e < 32*7; e += 64) {
    int r = e/7, k = e%7;
    int gr = rowbase + r;
    float v = 0.f;
    if (gr < UP_ROWS)
      v = isbf ? b2f(((const bf16*)upin)[(size_t)gr*7+k]) : ((const float*)upin)[(size_t)gr*7+k];
    intw[r*8+k] = v;
  }
  __syncthreads();

#pragma unroll
  for (int t = 0; t < 4; t++) {
    int c = t*32 + np;
    float s = S0c[c], b = H0c[c];
#pragma unroll
    for (int reg = 0; reg < 16; reg++) {
      int r = (reg&3) + 8*(reg>>2) + 4*hb2;
      float a = 0.f;
#pragma unroll
      for (int k = 0; k < 7; k++) a += intw[r*8+k]*w0s[c*9+k];
      float x = __sinf(a*s + b);
      uint hbi = f2bf_bits(x);
      uint lbi = f2bf_bits(x - __uint_as_float(hbi<<16));
      int col = (c & 3) | ((((c>>2) ^ r) & 31) << 2);
      actw[r*128 + col] = (hbi<<16) | lbi;
    }
  }

  for (int l = 0; l < 7; l++) {
    float sc[4], sh[4];
#pragma unroll
    for (int t=0;t<4;t++){ sc[t] = SRc[l*128 + t*32 + np]; sh[t] = HRc[l*128 + t*32 + np]; }
    Acc16 acc[4];
#pragma unroll
    for (int t=0;t<4;t++)
#pragma unroll
      for (int i=0;i<16;i++) acc[t].f[i] = 0.f;

#pragma unroll 1
    for (int Q = 0; Q < 4; Q++) {
#pragma unroll
      for (int ks = 0; ks < 2; ks++) {
        int g0 = (Q*32 + ks*16 + hb2*8) >> 2;
        uint4 a0 = *(const uint4*)&actw[np*128 + ((g0 ^ np) << 2)];
        uint4 a1 = *(const uint4*)&actw[np*128 + (((g0+1) ^ np) << 2)];
        uint au[8] = {a0.x,a0.y,a0.z,a0.w,a1.x,a1.y,a1.z,a1.w};
        FragAB ahi, alo;
#pragma unroll
        for (int p=0;p<4;p++){
          ahi.u[p] = (au[2*p]>>16)     | (au[2*p+1] & 0xFFFF0000u);
          alo.u[p] = (au[2*p]&0xFFFFu) | (au[2*p+1]<<16);
        }
        size_t fb = ((size_t)(((l*4 + Q)*2 + ks)*4) << 9) + (size_t)lane*8;
        FragB bh[4], bl[4];
#pragma unroll
        for (int t=0;t<4;t++){
          bh[t].q = *(const uint4*)(whi + fb + (size_t)t*512);
          bl[t].q = *(const uint4*)(wlo + fb + (size_t)t*512);
        }
#pragma unroll
        for (int t=0;t<4;t++){
          acc[t].v = __builtin_amdgcn_mfma_f32_32x32x16_bf16(ahi.v, bh[t].v, acc[t].v, 0,0,0);
          acc[t].v = __builtin_amdgcn_mfma_f32_32x32x16_bf16(alo.v, bh[t].v, acc[t].v, 0,0,0);
          acc[t].v = __builtin_amdgcn_mfma_f32_32x32x16_bf16(ahi.v, bl[t].v, acc[t].v, 0,0,0);
        }
      }
    }
#pragma unroll
    for (int t=0;t<4;t++){
      int c = t*32 + np;
#pragma unroll
      for (int reg=0;reg<16;reg++){
        int r = (reg&3) + 8*(reg>>2) + 4*hb2;
        float x = __sinf(acc[t].f[reg]*sc[t] + sh[t]);
        uint hbi = f2bf_bits(x);
        uint lbi = f2bf_bits(x - __uint_as_float(hbi<<16));
        int col = (c & 3) | ((((c>>2) ^ r) & 31) << 2);
        actw[r*128 + col] = (hbi<<16) | lbi;
      }
    }
    __syncthreads();
  }

  {
    float a = 0.f;
#pragma unroll
    for (int g = 0; g < 16; g++) {
      int gg = hb2*16 + g;
      uint4 u = *(const uint4*)&actw[np*128 + ((gg ^ np) << 2)];
      int kb = gg*4;
      float x0 = __uint_as_float(u.x & 0xFFFF0000u) + __uint_as_float(u.x<<16);
      float x1 = __uint_as_float(u.y & 0xFFFF0000u) + __uint_as_float(u.y<<16);
      float x2 = __uint_as_float(u.z & 0xFFFF0000u) + __uint_as_float(u.z<<16);
      float x3 = __uint_as_float(u.w & 0xFFFF0000u) + __uint_as_float(u.w<<16);
      a += x0*wfs[kb] + x1*wfs[kb+1] + x2*wfs[kb+2] + x3*wfs[kb+3];
    }
    a += __shfl_xor(a, 32, 64);
    int gr = rowbase + np;
    if (hb2 == 0 && gr < UP_ROWS) logits[gr] = a + bfs[0];
  }
}

// ---------------------------------------------------------------------------
__global__ void featin_k(const void* __restrict__ ldx, const void* __restrict__ pos,
                         float* __restrict__ xf, const int* __restrict__ flag){
  int i = blockIdx.x*256 + threadIdx.x;
  if (i >= N_PTS*35) return;
  int n = i / 35, c = i % 35;
  float v;
  if (flag[0]) {
    v = (c < 3) ? b2f(((const bf16*)ldx)[n*3+c]) : b2f(((const bf16*)pos)[n*32 + (c-3)]);
  } else {
    v = (c < 3) ? ((const float*)ldx)[n*3+c] : ((const float*)pos)[n*32 + (c-3)];
  }
  xf[(size_t)n*227 + c] = v;
}

__global__ void gather_e_k(const float* __restrict__ xf, int coff, int CIN,
                           const int* __restrict__ idx, float* __restrict__ e,
                           int n0, int np){
  int W2 = 2*CIN;
  int i = blockIdx.x*256 + threadIdx.x;
  if (i >= np*KNN_K*W2) return;
  int c = i % W2; int ek = i / W2;
  int nl = ek / KNN_K, k = ek % KNN_K;
  int n = n0 + nl;
  int j = idx[n*KNN_K + k];
  float out;
  if (c < CIN) out = xf[(size_t)j*227 + coff + c] - xf[(size_t)n*227 + coff + c];
  else         out = xf[(size_t)n*227 + coff + (c-CIN)];
  e[(size_t)ek*W2 + c] = out;
}

__global__ void kmax_k(const float* __restrict__ e2, int C, float* __restrict__ f1,
                       int n0, int np){
  int i = blockIdx.x*256 + threadIdx.x;
  if (i >= np*C) return;
  int nl = i / C, c = i % C;
  float v = -1e30f;
  for (int k=0;k<KNN_K;k++) v = fmaxf(v, e2[((size_t)nl*KNN_K+k)*C + c]);
  f1[(size_t)(n0+nl)*C + c] = v;
}

template<int C>
__global__ __launch_bounds__(256) void reduce1_k(const float* __restrict__ X, int n,
                                                 float* __restrict__ pmax, float* __restrict__ psum){
  const int tid = threadIdx.x;
  const int c = tid % C;
  const int r0 = tid / C;
  const int TPR = 256 / C;
  float vmax = -1e30f, vsum = 0.f;
  for (int row = blockIdx.x * TPR + r0; row < n; row += gridDim.x * TPR) {
    float v = X[(size_t)row * C + c];
    vmax = fmaxf(vmax, v); vsum += v;
  }
  __shared__ float smax[256], ssum[256];
  smax[tid]=vmax; ssum[tid]=vsum;
  __syncthreads();
  if (tid < C) {
    for (int q=1;q<TPR;q++){ vmax=fmaxf(vmax, smax[q*C+c]); vsum += ssum[q*C+c]; }
    pmax[blockIdx.x*C + c] = vmax; psum[blockIdx.x*C + c] = vsum;
  }
}

template<int C>
__global__ void reduce2_k(const float* __restrict__ pmax, const float* __restrict__ psum,
                          int nblk, float invn, float* __restrict__ fmaxo, float* __restrict__ favgo){
  int c = threadIdx.x; if (c >= C) return;
  float vmax=-1e30f, vsum=0.f;
  for (int b=0;b<nblk;b++){ vmax=fmaxf(vmax,pmax[b*C+c]); vsum+=psum[b*C+c]; }
  fmaxo[c]=vmax; favgo[c]=vsum*invn;
}

__global__ void concat_k(const float* __restrict__ xf, int coff, int CF,
                         const float* __restrict__ f1, int C,
                         const float* __restrict__ fmax, const float* __restrict__ favg,
                         float* __restrict__ h, int n0, int np){
  int W = CF + 3*C;
  int i = blockIdx.x*256 + threadIdx.x;
  if (i >= np*W) return;
  int nl = i / W, c = i % W;
  int n = n0 + nl;
  float v;
  if (c < CF)          v = xf[(size_t)n*227 + coff + c];
  else if (c < CF+C)   v = f1[(size_t)n*C + (c-CF)];
  else if (c < CF+2*C) v = fmax[c-CF-C];
  else                 v = favg[c-CF-2*C];
  h[(size_t)nl*W + c] = v;
}

__global__ void norms_k(const float* __restrict__ xf, float* __restrict__ nr){
  int n = blockIdx.x*256 + threadIdx.x;
  if (n >= N_PTS) return;
  const float* p = xf + (size_t)n*227 + 35;
  float s = 0.f;
  for (int d=0;d<64;d++) s += p[d]*p[d];
  nr[n] = s;
}

__global__ __launch_bounds__(64) void softgather_k(const float* __restrict__ logits,
                                                   const int* __restrict__ up_idx,
                                                   const float* __restrict__ xf,
                                                   float* __restrict__ z){
  __shared__ float lw[KUP]; __shared__ int li[KUP];
  int m = blockIdx.x;
  int tid = threadIdx.x;
  if (tid < KUP){ lw[tid] = logits[(size_t)m*KUP + tid]; li[tid] = up_idx[(size_t)m*KUP + tid]; }
  __syncthreads();
  float mx = -1e30f;
  for (int k=0;k<KUP;k++) mx = fmaxf(mx, lw[k]);
  __syncthreads();
  if (tid < KUP) lw[tid] = expf(lw[tid]-mx);
  __syncthreads();
  float s = 0.f;
  for (int k=0;k<KUP;k++) s += lw[k];
  float inv = 1.f/s;
  for (int c = tid; c < 227; c += 64){
    float acc = 0.f;
    for (int k=0;k<KUP;k++) acc += lw[k] * xf[(size_t)li[k]*227 + c];
    z[(size_t)m*227 + c] = acc*inv;
  }
}

__global__ void final_k(const float* __restrict__ h, const float* __restrict__ wf,
                        const float* __restrict__ bfp, void* __restrict__ out,
                        int r0, int rows, const int* __restrict__ flag){
  int m = blockIdx.x*256 + threadIdx.x;
  if (m >= rows) return;
  float hv[16];
#pragma unroll
  for (int d=0;d<16;d++) hv[d] = h[(size_t)m*16 + d];
#pragma unroll
  for (int o=0;o<3;o++){
    float acc = 0.f;
#pragma unroll
    for (int d=0;d<16;d++) acc += hv[d]*wf[o*16+d];
    float v = acc + bfp[o];
    if (!(fabsf(v) < 1e30f)) v = 777.0f;
    size_t oi = (size_t)(r0+m)*3+o;
    if (flag[0]) ((bf16*)out)[oi] = __float2bfloat16(v);
    else         ((float*)out)[oi] = v;
  }
}

// ---------------------------------------------------------------------------
extern "C" void kernel_launch(void* const* d_in, const int* in_sizes, int n_in,
                              void* d_out, int out_size, void* d_ws, size_t ws_size,
                              hipStream_t stream) {
  const int *idx0  = (const int*)d_in[3];
  const int *upidx = (const int*)d_in[37];

  // ---- workspace layout (floats) ----
  float* ws = (float*)d_ws;
  float* x_feat = ws;                     // [N,227]
  float* f1b    = ws + 3602944;           // [N,128]
  float* pmax   = ws + 5634560;
  float* psum   = ws + 5667328;
  float* fmaxv  = ws + 5700096;
  float* favgv  = ws + 5700224;
  int*   flag   = (int*)(ws + 5700352);
  int*   idx1   = (int*)(ws + 5700368);   // N*5
  float* nrm    = ws + 5779728;           // N
  float* logits = ws + 5795600;           // UP_ROWS
  float* wcvt   = ws + 6508352;           // 706,020 fp32 weights
  float* S      = ws + 7214400;           // scratch arena (9,662,464 floats)
  ushort_t* whi = (ushort_t*)(S + 9662464);   // siren planes (114688 each)
  ushort_t* wlo = whi + 114688;
  ushort_t* gwhi = wlo + 114688;              // generic W planes (601088 each)
  ushort_t* gwlo = gwhi + 601088;

  const size_t NEED = (size_t)(7214400 + 9662464) * 4
                    + (size_t)(114688*2 + 601088*2) * 2;   // ~70.4 MB
  if (ws_size < NEED) {
    fillmark_k<<<CDIV(out_size,256),256,0,stream>>>((bf16*)d_out, out_size);
    return;
  }

  // ---- dtype flag + one-shot weight conversion to fp32 ----
  flag_k<<<1,64,0,stream>>>((const uint*)d_in[2], flag);
  CvtTab tab;
  int wcoff = 0, seg = 0;
  auto CVT = [&](int i, int n)->const float* {
    tab.src[seg] = d_in[i]; tab.start[seg] = wcoff; seg++;
    const float* p = wcvt + wcoff; wcoff += n;
    return p;
  };
  const float *E0W1=CVT(4,8960),  *E0S1=CVT(5,128),  *E0H1=CVT(6,128),
              *E0W2=CVT(7,8192),  *E0B2=CVT(8,64);
  const float *F0W1=CVT(9,43584), *F0S1=CVT(10,192), *F0H1=CVT(11,192),
              *F0W2=CVT(12,24576),*F0S2=CVT(13,128), *F0H2=CVT(14,128),
              *F0W3=CVT(15,8192), *F0S3=CVT(16,64),  *F0H3=CVT(17,64),
              *F0W4=CVT(18,4096), *F0B4=CVT(19,64);
  const float *E1W1=CVT(20,32768),*E1S1=CVT(21,256), *E1H1=CVT(22,256),
              *E1W2=CVT(23,32768),*E1B2=CVT(24,128);
  const float *F1W1=CVT(25,172032),*F1S1=CVT(26,384),*F1H1=CVT(27,384),
              *F1W2=CVT(28,98304),*F1S2=CVT(29,256), *F1H2=CVT(30,256),
              *F1W3=CVT(31,32768),*F1S3=CVT(32,128), *F1H3=CVT(33,128),
              *F1W4=CVT(34,16384),*F1B4=CVT(35,128);
  const float *UPW0=CVT(38,896),  *UPS0=CVT(39,128), *UPH0=CVT(40,128),
              *UPWR=CVT(41,114688),*UPSR=CVT(42,896),*UPHR=CVT(43,896),
              *UPWF=CVT(44,128),  *UPBF=CVT(45,1);
  const float *DW0=CVT(46,58112), *DB0=CVT(47,256),
              *DW1=CVT(48,32768), *DB1=CVT(49,128),
              *DW2=CVT(50,8192),  *DB2=CVT(51,64),
              *DW3=CVT(52,2048),  *DB3=CVT(53,32),
              *DW4=CVT(54,512),   *DB4=CVT(55,16),
              *DWF=CVT(56,48),    *DBF=CVT(57,3);
  cvt_all_k<<<CDIV(wcoff,256),256,0,stream>>>(tab, wcvt, flag, wcoff);

  // siren planes
  packfrag_k<<<CDIV(114688,256),256,0,stream>>>(UPWR, whi, wlo, 114688);

  // generic W planes: pack all 17 GEMM weight matrices (order fixed)
  struct WP { const float* src; int N, K, Kpad, off; };
  WP wp[17]; int po = 0;
  auto ADDW = [&](const float* src, int N, int K, int Kpad)->int{
    int Npad = CDIV(N,32)*32;
    int idx = po;
    wp[idx%17] = {src, N, K, Kpad, 0};  // placeholder (filled below)
    return Npad*Kpad; (void)idx;
  };
  (void)ADDW;
  int offs[17]; const float* srcs[17]; int Ns[17], Ks[17], Kps[17];
  {
    int o = 0, q = 0;
    auto REG = [&](const float* s, int N, int K, int Kpad){
      srcs[q]=s; Ns[q]=N; Ks[q]=K; Kps[q]=Kpad; offs[q]=o;
      o += CDIV(N,32)*32*Kpad; q++;
    };
    REG(E0W1,128,70,96);   REG(E0W2,64,128,128);
    REG(F0W1,192,227,256); REG(F0W2,128,192,192); REG(F0W3,64,128,128); REG(F0W4,64,64,64);
    REG(E1W1,256,128,128); REG(E1W2,128,256,256);
    REG(F1W1,384,448,448); REG(F1W2,256,384,384); REG(F1W3,128,256,256); REG(F1W4,128,128,128);
    REG(DW0,256,227,256);  REG(DW1,128,256,256);  REG(DW2,64,128,128);
    REG(DW3,32,64,64);     REG(DW4,16,32,32);
  }
  for (int q = 0; q < 17; q++){
    int total = CDIV(Ns[q],32)*32*Kps[q];
    packw_mfma_k<<<CDIV(total,256),256,0,stream>>>(srcs[q], gwhi+offs[q], gwlo+offs[q],
                                                   Ns[q], Ks[q], Kps[q], total);
  }
  #define PW(i) (gwhi+offs[i]), (gwlo+offs[i])

  const float invN = 1.f/(float)N_PTS;
  const int CHP = 3968;    // edge-phase point chunk (4 chunks)
  const int CHN = 8192;    // fc-phase row chunk
  const int CHD = 12288;   // decoder row chunk (3 chunks)

  featin_k<<<CDIV(N_PTS*35,256),256,0,stream>>>(d_in[1], d_in[2], x_feat, flag);

  // ---- phase 1: emb block 0
  for (int n0 = 0; n0 < N_PTS; n0 += CHP) {
    int np = N_PTS - n0; if (np > CHP) np = CHP;
    int ne = np * KNN_K;
    float* eA = S;                       // [ne,70] then [ne,64]
    float* eB = S + 1388800;             // [ne,128]
    gather_e_k<<<CDIV(ne*70,256),256,0,stream>>>(x_feat, 0, 35, idx0, eA, n0, np);
    gemm_mfma_k<0,1><<<dim3(CDIV(ne,128),1),256,0,stream>>>(eA,70, ne,70, PW(0),96,  E0S1,E0H1,0.f, eB,128, 128);
    gemm_mfma_k<1,0><<<dim3(CDIV(ne,128),1),256,0,stream>>>(eB,128, ne,128, PW(1),128, nullptr,E0B2,0.f, eA,64, 64);
    kmax_k<<<CDIV(np*64,256),256,0,stream>>>(eA, 64, f1b, n0, np);
  }
  reduce1_k<64><<<256,256,0,stream>>>(f1b, N_PTS, pmax, psum);
  reduce2_k<64><<<1,64,0,stream>>>(pmax, psum, 256, invN, fmaxv, favgv);
  for (int n0 = 0; n0 < N_PTS; n0 += CHN) {
    int np = N_PTS - n0; if (np > CHN) np = CHN;
    float* h  = S;
    float* a1 = S + 1859584;
    int gx = CDIV(np,128);
    concat_k<<<CDIV(np*227,256),256,0,stream>>>(x_feat,0,35, f1b,64, fmaxv,favgv, h, n0, np);
    gemm_mfma_k<0,1><<<dim3(gx,2),256,0,stream>>>(h,227,  np,227, PW(2),256, F0S1,F0H1,0.f, a1,192, 192);
    gemm_mfma_k<0,1><<<dim3(gx,1),256,0,stream>>>(a1,192, np,192, PW(3),192, F0S2,F0H2,0.f, h,128,  128);
    gemm_mfma_k<0,1><<<dim3(gx,1),256,0,stream>>>(h,128,  np,128, PW(4),128, F0S3,F0H3,0.f, a1,64,  64);
    gemm_mfma_k<1,0><<<dim3(gx,1),256,0,stream>>>(a1,64,  np,64,  PW(5),64,  nullptr,F0B4,0.f, x_feat+(size_t)n0*227+35,227, 64);
  }

  // ---- phase 2: dynamic KNN (MFMA)
  norms_k<<<CDIV(N_PTS,256),256,0,stream>>>(x_feat, nrm);
  {
    const int PLANE = NTILE*5*64*8;
    ushort_t* ajhi = (ushort_t*)S;
    ushort_t* ajlo = ajhi + PLANE;
    ushort_t* bihi = ajlo + PLANE;
    ushort_t* bilo = bihi + PLANE;
    packknn_k<<<CDIV(PLANE,256),256,0,stream>>>(x_feat, nrm, ajhi, ajlo, bihi, bilo);
    knn_mfma_k<<<NTILE,256,0,stream>>>(ajhi, ajlo, bihi, bilo, idx1);
  }

  // ---- phase 3: emb block 1
  for (int n0 = 0; n0 < N_PTS; n0 += CHP) {
    int np = N_PTS - n0; if (np > CHP) np = CHP;
    int ne = np * KNN_K;
    float* eA = S;                       // [ne,128]
    float* eB = S + 2539520;             // [ne,256]
    gather_e_k<<<CDIV(ne*128,256),256,0,stream>>>(x_feat, 35, 64, idx1, eA, n0, np);
    gemm_mfma_k<0,1><<<dim3(CDIV(ne,128),2),256,0,stream>>>(eA,128, ne,128, PW(6),128, E1S1,E1H1,0.f, eB,256, 256);
    gemm_mfma_k<1,0><<<dim3(CDIV(ne,128),1),256,0,stream>>>(eB,256, ne,256, PW(7),256, nullptr,E1B2,0.f, eA,128, 128);
    kmax_k<<<CDIV(np*128,256),256,0,stream>>>(eA, 128, f1b, n0, np);
  }
  reduce1_k<128><<<256,256,0,stream>>>(f1b, N_PTS, pmax, psum);
  reduce2_k<128><<<1,128,0,stream>>>(pmax, psum, 256, invN, fmaxv, favgv);
  for (int n0 = 0; n0 < N_PTS; n0 += CHN) {
    int np = N_PTS - n0; if (np > CHN) np = CHN;
    float* h  = S;
    float* a1 = S + 3670016;
    int gx = CDIV(np,128);
    concat_k<<<CDIV(np*448,256),256,0,stream>>>(x_feat,35,64, f1b,128, fmaxv,favgv, h, n0, np);
    gemm_mfma_k<0,1><<<dim3(gx,3),256,0,stream>>>(h,448,  np,448, PW(8),448,  F1S1,F1H1,0.f, a1,384, 384);
    gemm_mfma_k<0,1><<<dim3(gx,2),256,0,stream>>>(a1,384, np,384, PW(9),384,  F1S2,F1H2,0.f, h,256,  256);
    gemm_mfma_k<0,1><<<dim3(gx,1),256,0,stream>>>(h,256,  np,256, PW(10),256, F1S3,F1H3,0.f, a1,128, 128);
    gemm_mfma_k<1,0><<<dim3(gx,1),256,0,stream>>>(a1,128, np,128, PW(11),128, nullptr,F1B4,0.f, x_feat+(size_t)n0*227+99,227, 128);
  }

  // ---- phase 4: fused SIREN -> logits; softmax gather -> z
  siren_fused_k<<<CDIV(UP_ROWS,128),256,0,stream>>>(
      d_in[36], whi, wlo, UPW0, UPS0, UPH0, UPSR, UPHR, UPWF, UPBF, logits, flag);
  float* zbuf = S;                 // [M,227]
  softgather_k<<<M_PTS,64,0,stream>>>(logits, upidx, x_feat, zbuf);

  // ---- phase 5: SIREN decoder (MFMA, 3 chunks; A aliases dead x_feat)
  {
    float* A  = ws;                      // [CHD,256] <= x_feat region (dead now)
    float* Bb = S + 8089600;             // [CHD,128] (after zbuf)
    for (int r0 = 0; r0 < M_PTS; r0 += CHD) {
      int rows = M_PTS - r0; if (rows > CHD) rows = CHD;
      int gx = CDIV(rows,128);
      gemm_mfma_k<2,2><<<dim3(gx,2),256,0,stream>>>(zbuf + (size_t)r0*227,227, rows,227, PW(12),256, nullptr,DB0,30.f, A,256, 256);
      gemm_mfma_k<1,2><<<dim3(gx,1),256,0,stream>>>(A,256,  rows,256, PW(13),256, nullptr,DB1,0.f, Bb,128, 128);
      gemm_mfma_k<1,2><<<dim3(gx,1),256,0,stream>>>(Bb,128, rows,128, PW(14),128, nullptr,DB2,0.f, A,64,   64);
      gemm_mfma_k<1,2><<<dim3(gx,1),256,0,stream>>>(A,64,   rows,64,  PW(15),64,  nullptr,DB3,0.f, Bb,32,  32);
      gemm_mfma_k<1,2><<<dim3(gx,1),256,0,stream>>>(Bb,32,  rows,32,  PW(16),32,  nullptr,DB4,0.f, A,16,   16);
      final_k<<<CDIV(rows,256),256,0,stream>>>(A, DWF, DBF, d_out, r0, rows, flag);
    }
  }
}

// Round 9
// 2409.855 us; speedup vs baseline: 1.4741x; 1.4741x over previous
//
#include <hip/hip_runtime.h>
#include <hip/hip_bf16.h>
#include <math.h>

#define N_PTS 15872
#define M_PTS 35637
#define KNN_K 5
#define KUP   20
#define UP_ROWS (M_PTS * KUP)   // 712740
#define NTILE (N_PTS/32)        // 496 i/j tiles
#define CDIV(a,b) (((a)+(b)-1)/(b))

typedef __hip_bfloat16 bf16;
typedef unsigned int uint;
typedef unsigned short ushort_t;
__device__ __forceinline__ float b2f(bf16 x){ return __bfloat162float(x); }

// round-to-nearest-even fp32 -> bf16 bit pattern (finite inputs)
__device__ __forceinline__ uint f2bf_bits(float x){
  uint u = __float_as_uint(x);
  return (u + 0x7FFFu + ((u>>16)&1u)) >> 16;
}

typedef __attribute__((ext_vector_type(8))) short bf16x8;
typedef __attribute__((ext_vector_type(16))) float f32x16;
union FragAB { bf16x8 v; uint u[4]; };
union FragB  { bf16x8 v; uint4 q; };
union Acc16  { f32x16 v; float f[16]; };

// ---------------------------------------------------------------------------
__global__ void flag_k(const uint* __restrict__ pos_raw, int* __restrict__ flag){
  if (threadIdx.x == 0 && blockIdx.x == 0)
    flag[0] = (pos_raw[0] == 0x3F800000u) ? 1 : 0;
}

struct CvtTab { const void* src[52]; int start[52]; };
__global__ __launch_bounds__(256) void cvt_all_k(CvtTab tab, float* __restrict__ dst,
                                                 const int* __restrict__ flag, int total){
  int i = blockIdx.x*256 + threadIdx.x;
  if (i >= total) return;
  int s = 0;
#pragma unroll 1
  for (int k = 1; k < 52; k++) if (tab.start[k] <= i) s = k;
  int off = i - tab.start[s];
  float v = flag[0] ? b2f(((const bf16*)tab.src[s])[off]) : ((const float*)tab.src[s])[off];
  dst[i] = v;
}

// pack SIREN 128x128 weights into frag-major split-bf16 hi/lo planes.
__global__ void packfrag_k(const float* __restrict__ w, ushort_t* __restrict__ whi,
                           ushort_t* __restrict__ wlo, int n){
  int i = blockIdx.x*256 + threadIdx.x;
  if (i >= n) return;
  int j = i & 7;
  int lam = (i >> 3) & 63;
  int fg = i >> 9;
  int t = fg & 3, ks = (fg >> 2) & 1, Q = (fg >> 3) & 3, l = fg >> 5;
  int nn = t*32 + (lam & 31);
  int kk = Q*32 + ks*16 + (lam >> 5)*8 + j;
  float x = w[l*16384 + nn*128 + kk];
  uint hb = f2bf_bits(x);
  uint lb = f2bf_bits(x - __uint_as_float(hb << 16));
  whi[i] = (ushort_t)hb;
  wlo[i] = (ushort_t)lb;
}

// generic frag-major split-bf16 pack for weight matrix W[N][K] (row-major),
// K padded to Kpad (x32), N padded to x32 with zeros.
__global__ void packw_mfma_k(const float* __restrict__ w, ushort_t* __restrict__ whi,
                             ushort_t* __restrict__ wlo, int N, int K, int Kpad, int total){
  int i = blockIdx.x*256 + threadIdx.x;
  if (i >= total) return;
  int j = i & 7;
  int lane = (i >> 3) & 63;
  int fr = i >> 9;
  int nq = Kpad >> 5;
  int ks = fr & 1;
  int q  = (fr >> 1) % nq;
  int nt = (fr >> 1) / nq;
  int n = nt*32 + (lane & 31);
  int k = q*32 + ks*16 + (lane >> 5)*8 + j;
  float x = (n < N && k < K) ? w[(size_t)n*K + k] : 0.f;
  uint hb = f2bf_bits(x);
  uint lb = f2bf_bits(x - __uint_as_float(hb << 16));
  whi[i] = (ushort_t)hb;
  wlo[i] = (ushort_t)lb;
}

// pack KNN features into frag-major split-bf16 planes with norm augmentation.
__global__ void packknn_k(const float* __restrict__ xf, const float* __restrict__ nr,
                          ushort_t* __restrict__ ahi, ushort_t* __restrict__ alo,
                          ushort_t* __restrict__ bhi, ushort_t* __restrict__ blo){
  int i = blockIdx.x*256 + threadIdx.x;
  if (i >= NTILE*5*64*8) return;
  int e = i & 7;
  int lane = (i >> 3) & 63;
  int rest = i >> 9;
  int kc = rest % 5, jt = rest / 5;
  int n = jt*32 + (lane & 31);
  int k = kc*16 + (lane >> 5)*8 + e;
  float f = (k < 64) ? xf[(size_t)n*227 + 35 + k] : 0.f;
  float av, bv;
  if (k < 64)      { av = 2.f*f;   bv = f; }
  else if (k == 64){ av = nr[n];   bv = -1.f; }
  else if (k == 65){ av = 1.f;     bv = -nr[n]; }
  else             { av = 0.f;     bv = 0.f; }
  uint ah = f2bf_bits(av); uint al = f2bf_bits(av - __uint_as_float(ah<<16));
  uint bh = f2bf_bits(bv); uint bl = f2bf_bits(bv - __uint_as_float(bh<<16));
  ahi[i] = (ushort_t)ah; alo[i] = (ushort_t)al;
  bhi[i] = (ushort_t)bh; blo[i] = (ushort_t)bl;
}

__global__ void fillmark_k(bf16* __restrict__ out, int n){
  int i = blockIdx.x*256 + threadIdx.x;
  if (i < n) out[i] = __float2bfloat16(12345.0f);
}

// ---------------------------------------------------------------------------
// fp32 fused GEMM (round-7 proven; used for edge + fc1 stacks)
// ---------------------------------------------------------------------------
template<int EPI, int ACT>
__global__ __launch_bounds__(256) void gemm_k(
    const float* __restrict__ A, int lda,
    const float* __restrict__ W, int ldw,
    const float* __restrict__ scale, const float* __restrict__ shift,
    float gmul, float* __restrict__ C, int ldc,
    int M, int Nout, int K)
{
  __shared__ __align__(16) float As[16][64];
  __shared__ __align__(16) float Ws[16][64];
  const int tid = threadIdx.x;
  const int tx = tid & 15, ty = tid >> 4;
  const int bm = blockIdx.x * 64, bn = blockIdx.y * 64;
  const int ar = tid >> 2, ak = (tid & 3) * 4;
  float acc[4][4] = {};
  for (int k0 = 0; k0 < K; k0 += 16) {
    float a0=0.f,a1=0.f,a2=0.f,a3=0.f;
    int grow = bm + ar;
    if (grow < M) {
      const float* ap = A + (size_t)grow * lda + (k0 + ak);
      int rem = K - (k0 + ak);
      if (rem >= 4) { a0=ap[0]; a1=ap[1]; a2=ap[2]; a3=ap[3]; }
      else { if(rem>0)a0=ap[0]; if(rem>1)a1=ap[1]; if(rem>2)a2=ap[2]; }
    }
    float w0=0.f,w1=0.f,w2=0.f,w3=0.f;
    int gn = bn + ar;
    if (gn < Nout) {
      const float* wp = W + (size_t)gn * ldw + (k0 + ak);
      int rem = K - (k0 + ak);
      if (rem >= 4) { w0=wp[0]; w1=wp[1]; w2=wp[2]; w3=wp[3]; }
      else { if(rem>0)w0=wp[0]; if(rem>1)w1=wp[1]; if(rem>2)w2=wp[2]; }
    }
    __syncthreads();
    As[ak+0][ar]=a0; As[ak+1][ar]=a1; As[ak+2][ar]=a2; As[ak+3][ar]=a3;
    Ws[ak+0][ar]=w0; Ws[ak+1][ar]=w1; Ws[ak+2][ar]=w2; Ws[ak+3][ar]=w3;
    __syncthreads();
#pragma unroll
    for (int kk = 0; kk < 16; kk++) {
      float4 av = *reinterpret_cast<const float4*>(&As[kk][ty*4]);
      float4 wv = *reinterpret_cast<const float4*>(&Ws[kk][tx*4]);
      float aa[4] = {av.x,av.y,av.z,av.w};
      float ww[4] = {wv.x,wv.y,wv.z,wv.w};
#pragma unroll
      for (int i=0;i<4;i++)
#pragma unroll
        for (int j=0;j<4;j++) acc[i][j] += aa[i]*ww[j];
    }
  }
#pragma unroll
  for (int i=0;i<4;i++){
    int m = bm + ty*4 + i;
    if (m >= M) continue;
#pragma unroll
    for (int j=0;j<4;j++){
      int n = bn + tx*4 + j;
      if (n >= Nout) continue;
      float v = acc[i][j];
      if (EPI==0)      v = v * scale[n] + shift[n];
      else if (EPI==1) v = v + shift[n];
      else             v = (v + shift[n]) * gmul;
      if (ACT==1)      v = v > 0.f ? v : 0.2f*v;
      else if (ACT==2) v = sinf(v);
      C[(size_t)m*ldc + n] = v;
    }
  }
}

// ---------------------------------------------------------------------------
// Generic fused per-row MLP (siren-style): up to 6 layers, dims <= 256.
// Block 256 = 4 waves: wave = (row-half, tile-half). 64 rows/block.
// Activations packed split-bf16 u32 in swizzled LDS slab [64][256].
// W from frag-major hi/lo planes; per-layer epi/act from table.
// OUTMODE 0: final layer -> fp32 Cout[row*ldc+col].
// OUTMODE 1: final layer -> flagged bf16/fp32 at oflg[row*3+col] (canary).
// ---------------------------------------------------------------------------
struct MLayer { int K, N, Kq, Nt, woff, soff, hoff, epi, act; float gmul; };
struct MCfg { MLayer L[6]; };

template<int NL, int OUTMODE>
__global__ __launch_bounds__(256) void mlp_fused_k(
    const float* __restrict__ A0, int lda0, int K0, int M,
    MCfg cfg,
    const ushort_t* __restrict__ wh, const ushort_t* __restrict__ wl,
    const float* __restrict__ wc,
    float* __restrict__ Cout, int ldc,
    void* __restrict__ oflg, const int* __restrict__ flag)
{
  __shared__ __align__(16) uint slab[64*256];   // 65536 B
  const int tid = threadIdx.x;
  const int lane = tid & 63;
  const int wv = tid >> 6;
  const int np = lane & 31;
  const int hb2 = lane >> 5;
  const int rhalf = wv & 1, thalf = wv >> 1;
  const int rb = blockIdx.x * 64;
  const int row_l = rhalf*32 + np;

  // stage input: fp32 -> split-packed u32, swizzled; zero-pad cols [K0,256)
  for (int e = tid; e < 64*64; e += 256) {
    int r = e >> 6, g = e & 63;
    int gr = rb + r;
    uint p[4];
#pragma unroll
    for (int u=0;u<4;u++){
      int k = g*4+u;
      float f = (gr < M && k < K0) ? A0[(size_t)gr*lda0 + k] : 0.f;
      uint hb = f2bf_bits(f);
      uint lb = f2bf_bits(f - __uint_as_float(hb<<16));
      p[u] = (hb<<16) | lb;
    }
    *(uint4*)&slab[r*256 + (((g ^ r) & 63)<<2)] = make_uint4(p[0],p[1],p[2],p[3]);
  }
  __syncthreads();

#pragma unroll 1
  for (int l = 0; l < NL; l++){
    const int N = cfg.L[l].N, Kq = cfg.L[l].Kq, Nt = cfg.L[l].Nt;
    const int woff = cfg.L[l].woff, soff = cfg.L[l].soff, hoff = cfg.L[l].hoff;
    const int epi = cfg.L[l].epi, actf = cfg.L[l].act;
    const float gmul = cfg.L[l].gmul;
    Acc16 acc[4];
#pragma unroll
    for (int u=0;u<4;u++)
#pragma unroll
      for (int i=0;i<16;i++) acc[u].f[i] = 0.f;

#pragma unroll 1
    for (int q = 0; q < Kq; q++){
#pragma unroll
      for (int ks = 0; ks < 2; ks++){
        int g0 = (q*32 + ks*16 + hb2*8) >> 2;
        uint4 a0 = *(const uint4*)&slab[row_l*256 + ((((g0  ) ^ row_l) & 63)<<2)];
        uint4 a1 = *(const uint4*)&slab[row_l*256 + ((((g0+1) ^ row_l) & 63)<<2)];
        uint au[8] = {a0.x,a0.y,a0.z,a0.w,a1.x,a1.y,a1.z,a1.w};
        FragAB ah, al;
#pragma unroll
        for (int p=0;p<4;p++){
          ah.u[p] = (au[2*p]>>16)     | (au[2*p+1] & 0xFFFF0000u);
          al.u[p] = (au[2*p]&0xFFFFu) | (au[2*p+1]<<16);
        }
#pragma unroll
        for (int u=0;u<4;u++){
          int t = thalf + u*2;
          if (t < Nt){
            size_t fb = (size_t)woff + ((size_t)((t*Kq + q)*2 + ks))*512 + (size_t)lane*8;
            FragB bh, bl;
            bh.q = *(const uint4*)(wh + fb);
            bl.q = *(const uint4*)(wl + fb);
            acc[u].v = __builtin_amdgcn_mfma_f32_32x32x16_bf16(ah.v, bh.v, acc[u].v, 0,0,0);
            acc[u].v = __builtin_amdgcn_mfma_f32_32x32x16_bf16(al.v, bh.v, acc[u].v, 0,0,0);
            acc[u].v = __builtin_amdgcn_mfma_f32_32x32x16_bf16(ah.v, bl.v, acc[u].v, 0,0,0);
          }
        }
      }
    }
    __syncthreads();  // all slab reads (both tile-half waves of a row) done
#pragma unroll
    for (int u=0;u<4;u++){
      int t = thalf + u*2;
      if (t < Nt){
        int col = t*32 + np;
        if (col < N){
          float scv = (epi==0) ? wc[soff+col] : 0.f;
          float shv = wc[hoff+col];
#pragma unroll
          for (int reg=0;reg<16;reg++){
            int r32 = (reg&3) + 8*(reg>>2) + 4*hb2;
            float v = acc[u].f[reg];
            if (epi==0)      v = v*scv + shv;
            else if (epi==1) v = v + shv;
            else             v = (v + shv)*gmul;
            if (actf==1)      v = v > 0.f ? v : 0.2f*v;
            else if (actf==2) v = __sinf(v);
            if (l == NL-1){
              int gr = rb + rhalf*32 + r32;
              if (gr < M){
                if (OUTMODE==0) Cout[(size_t)gr*ldc + col] = v;
                else {
                  if (!(fabsf(v) < 1e30f)) v = 777.0f;  // canary
                  size_t oi = (size_t)gr*3 + col;
                  if (flag[0]) ((bf16*)oflg)[oi] = __float2bfloat16(v);
                  else         ((float*)oflg)[oi] = v;
                }
              }
            } else {
              int r = rhalf*32 + r32;
              uint hb = f2bf_bits(v);
              uint lb = f2bf_bits(v - __uint_as_float(hb<<16));
              slab[r*256 + ((((col>>2) ^ r) & 63)<<2) + (col&3)] = (hb<<16) | lb;
            }
          }
        }
      }
    }
    __syncthreads();
  }
}

// ---------------------------------------------------------------------------
// MFMA KNN (validated round 7).
// ---------------------------------------------------------------------------
#define INS5(tv, tj, v, j) \
  if ((v) > tv[4]){ tv[4]=(v); tj[4]=(j); \
    _Pragma("unroll") \
    for (int q=4;q>0;q--) \
      if (tv[q] > tv[q-1]){ float tf=tv[q-1]; tv[q-1]=tv[q]; tv[q]=tf; \
                            int ti=tj[q-1]; tj[q-1]=tj[q]; tj[q]=ti; } }

__global__ __launch_bounds__(256) void knn_mfma_k(
    const ushort_t* __restrict__ ahi, const ushort_t* __restrict__ alo,
    const ushort_t* __restrict__ bhi, const ushort_t* __restrict__ blo,
    int* __restrict__ out)
{
  __shared__ float mv[4][32][5];
  __shared__ int   mjj[4][32][5];
  const int tid = threadIdx.x;
  const int lane = tid & 63;
  const int wv = tid >> 6;
  const int np = lane & 31;
  const int hb2 = lane >> 5;
  const int it = blockIdx.x;
  const int ig = it*32 + np;

  FragB vh[5], vl[5];
  {
    size_t bb = (size_t)(it*5)*512 + (size_t)lane*8;
#pragma unroll
    for (int kc=0;kc<5;kc++){
      vh[kc].q = *(const uint4*)(bhi + bb + kc*512);
      vl[kc].q = *(const uint4*)(blo + bb + kc*512);
    }
  }

  float tv[5] = {-1e30f,-1e30f,-1e30f,-1e30f,-1e30f};
  int   tj[5] = {0,0,0,0,0};

  FragB uh[5], ul[5], nh[5], nl[5];
  {
    size_t ab = (size_t)(wv*5)*512 + (size_t)lane*8;
#pragma unroll
    for (int kc=0;kc<5;kc++){
      uh[kc].q = *(const uint4*)(ahi + ab + kc*512);
      ul[kc].q = *(const uint4*)(alo + ab + kc*512);
    }
  }

#pragma unroll 1
  for (int t = 0; t < NTILE/4; t++){
    int jt = wv + t*4;
    if (t+1 < NTILE/4){
      size_t an = (size_t)((jt+4)*5)*512 + (size_t)lane*8;
#pragma unroll
      for (int kc=0;kc<5;kc++){
        nh[kc].q = *(const uint4*)(ahi + an + kc*512);
        nl[kc].q = *(const uint4*)(alo + an + kc*512);
      }
    }
    Acc16 acc;
#pragma unroll
    for (int q=0;q<16;q++) acc.f[q] = 0.f;
#pragma unroll
    for (int kc=0;kc<5;kc++){
      acc.v = __builtin_amdgcn_mfma_f32_32x32x16_bf16(uh[kc].v, vh[kc].v, acc.v, 0,0,0);
      acc.v = __builtin_amdgcn_mfma_f32_32x32x16_bf16(ul[kc].v, vh[kc].v, acc.v, 0,0,0);
      acc.v = __builtin_amdgcn_mfma_f32_32x32x16_bf16(uh[kc].v, vl[kc].v, acc.v, 0,0,0);
    }
    int jb = jt*32 + 4*hb2;
#pragma unroll
    for (int reg=0;reg<16;reg++){
      int j = jb + (reg&3) + 8*(reg>>2);
      float v = acc.f[reg];
      if (j != ig) { INS5(tv, tj, v, j); }
    }
    if (t+1 < NTILE/4){
#pragma unroll
      for (int kc=0;kc<5;kc++){ uh[kc] = nh[kc]; ul[kc] = nl[kc]; }
    }
  }

#pragma unroll
  for (int s=0;s<5;s++){
    float ov = __shfl_xor(tv[s], 32, 64);
    int   oj = __shfl_xor(tj[s], 32, 64);
    INS5(tv, tj, ov, oj);
  }
  if (hb2 == 0){
#pragma unroll
    for (int s=0;s<5;s++){ mv[wv][np][s] = tv[s]; mjj[wv][np][s] = tj[s]; }
  }
  __syncthreads();
  if (tid < 32){
    float bv[5]; int bj[5];
#pragma unroll
    for (int s=0;s<5;s++){ bv[s] = mv[0][tid][s]; bj[s] = mjj[0][tid][s]; }
#pragma unroll
    for (int w=1;w<4;w++)
#pragma unroll
      for (int s=0;s<5;s++){
        float v = mv[w][tid][s]; int j = mjj[w][tid][s];
        INS5(bv, bj, v, j);
      }
    int gi = it*32 + tid;
#pragma unroll
    for (int s=0;s<5;s++) out[gi*KNN_K + s] = bj[s];
  }
}

// ---------------------------------------------------------------------------
// Fused 8-layer SIREN + head (validated round 5/7).
// ---------------------------------------------------------------------------
__global__ __launch_bounds__(256, 2) void siren_fused_k(
    const void* __restrict__ upin,
    const ushort_t* __restrict__ whi, const ushort_t* __restrict__ wlo,
    const float* __restrict__ W0c, const float* __restrict__ S0c, const float* __restrict__ H0c,
    const float* __restrict__ SRc, const float* __restrict__ HRc,
    const float* __restrict__ WFc, const float* __restrict__ BFc,
    float* __restrict__ logits, const int* __restrict__ flag)
{
  __shared__ __align__(16) uint act[4*32*128];
  __shared__ float intile[4*32*8];
  __shared__ float w0s[128*9];
  __shared__ float wfs[128];
  __shared__ float bfs[1];

  const int tid  = threadIdx.x;
  const int lane = tid & 63;
  const int wv   = tid >> 6;
  const int np   = lane & 31;
  const int hb2  = lane >> 5;
  const int rowbase = blockIdx.x * 128 + wv * 32;
  const int isbf = flag[0];
  uint*  actw = act + wv*32*128;
  float* intw = intile + wv*32*8;

  for (int e = tid; e < 128*7; e += 256) w0s[(e/7)*9 + (e%7)] = W0c[e];
  if (tid < 128) wfs[tid] = WFc[tid];
  if (tid == 0) bfs[0] = BFc[0];
  for (int e = lane; e < 32*7; e += 64) {
    int r = e/7, k = e%7;
    int gr = rowbase + r;
    float v = 0.f;
    if (gr < UP_ROWS)
      v = isbf ? b2f(((const bf16*)upin)[(size_t)gr*7+k]) : ((const float*)upin)[(size_t)gr*7+k];
    intw[r*8+k] = v;
  }
  __syncthreads();

#pragma unroll
  for (int t = 0; t < 4; t++) {
    int c = t*32 + np;
    float s = S0c[c], b = H0c[c];
#pragma unroll
    for (int reg = 0; reg < 16; reg++) {
      int r = (reg&3) + 8*(reg>>2) + 4*hb2;
      float a = 0.f;
#pragma unroll
      for (int k = 0; k < 7; k++) a += intw[r*8+k]*w0s[c*9+k];
      float x = __sinf(a*s + b);
      uint hbi = f2bf_bits(x);
      uint lbi = f2bf_bits(x - __uint_as_float(hbi<<16));
      int col = (c & 3) | ((((c>>2) ^ r) & 31) << 2);
      actw[r*128 + col] = (hbi<<16) | lbi;
    }
  }

  for (int l = 0; l < 7; l++) {
    float sc[4], sh[4];
#pragma unroll
    for (int t=0;t<4;t++){ sc[t] = SRc[l*128 + t*32 + np]; sh[t] = HRc[l*128 + t*32 + np]; }
    Acc16 acc[4];
#pragma unroll
    for (int t=0;t<4;t++)
#pragma unroll
      for (int i=0;i<16;i++) acc[t].f[i] = 0.f;

#pragma unroll 1
    for (int Q = 0; Q < 4; Q++) {
#pragma unroll
      for (int ks = 0; ks < 2; ks++) {
        int g0 = (Q*32 + ks*16 + hb2*8) >> 2;
        uint4 a0 = *(const uint4*)&actw[np*128 + ((g0 ^ np) << 2)];
        uint4 a1 = *(const uint4*)&actw[np*128 + (((g0+1) ^ np) << 2)];
        uint au[8] = {a0.x,a0.y,a0.z,a0.w,a1.x,a1.y,a1.z,a1.w};
        FragAB ahi, alo;
#pragma unroll
        for (int p=0;p<4;p++){
          ahi.u[p] = (au[2*p]>>16)     | (au[2*p+1] & 0xFFFF0000u);
          alo.u[p] = (au[2*p]&0xFFFFu) | (au[2*p+1]<<16);
        }
        size_t fb = ((size_t)(((l*4 + Q)*2 + ks)*4) << 9) + (size_t)lane*8;
        FragB bh[4], bl[4];
#pragma unroll
        for (int t=0;t<4;t++){
          bh[t].q = *(const uint4*)(whi + fb + (size_t)t*512);
          bl[t].q = *(const uint4*)(wlo + fb + (size_t)t*512);
        }
#pragma unroll
        for (int t=0;t<4;t++){
          acc[t].v = __builtin_amdgcn_mfma_f32_32x32x16_bf16(ahi.v, bh[t].v, acc[t].v, 0,0,0);
          acc[t].v = __builtin_amdgcn_mfma_f32_32x32x16_bf16(alo.v, bh[t].v, acc[t].v, 0,0,0);
          acc[t].v = __builtin_amdgcn_mfma_f32_32x32x16_bf16(ahi.v, bl[t].v, acc[t].v, 0,0,0);
        }
      }
    }
#pragma unroll
    for (int t=0;t<4;t++){
      int c = t*32 + np;
#pragma unroll
      for (int reg=0;reg<16;reg++){
        int r = (reg&3) + 8*(reg>>2) + 4*hb2;
        float x = __sinf(acc[t].f[reg]*sc[t] + sh[t]);
        uint hbi = f2bf_bits(x);
        uint lbi = f2bf_bits(x - __uint_as_float(hbi<<16));
        int col = (c & 3) | ((((c>>2) ^ r) & 31) << 2);
        actw[r*128 + col] = (hbi<<16) | lbi;
      }
    }
    __syncthreads();
  }

  {
    float a = 0.f;
#pragma unroll
    for (int g = 0; g < 16; g++) {
      int gg = hb2*16 + g;
      uint4 u = *(const uint4*)&actw[np*128 + ((gg ^ np) << 2)];
      int kb = gg*4;
      float x0 = __uint_as_float(u.x & 0xFFFF0000u) + __uint_as_float(u.x<<16);
      float x1 = __uint_as_float(u.y & 0xFFFF0000u) + __uint_as_float(u.y<<16);
      float x2 = __uint_as_float(u.z & 0xFFFF0000u) + __uint_as_float(u.z<<16);
      float x3 = __uint_as_float(u.w & 0xFFFF0000u) + __uint_as_float(u.w<<16);
      a += x0*wfs[kb] + x1*wfs[kb+1] + x2*wfs[kb+2] + x3*wfs[kb+3];
    }
    a += __shfl_xor(a, 32, 64);
    int gr = rowbase + np;
    if (hb2 == 0 && gr < UP_ROWS) logits[gr] = a + bfs[0];
  }
}

// ---------------------------------------------------------------------------
__global__ void featin_k(const void* __restrict__ ldx, const void* __restrict__ pos,
                         float* __restrict__ xf, const int* __restrict__ flag){
  int i = blockIdx.x*256 + threadIdx.x;
  if (i >= N_PTS*35) return;
  int n = i / 35, c = i % 35;
  float v;
  if (flag[0]) {
    v = (c < 3) ? b2f(((const bf16*)ldx)[n*3+c]) : b2f(((const bf16*)pos)[n*32 + (c-3)]);
  } else {
    v = (c < 3) ? ((const float*)ldx)[n*3+c] : ((const float*)pos)[n*32 + (c-3)];
  }
  xf[(size_t)n*227 + c] = v;
}

__global__ void gather_e_k(const float* __restrict__ xf, int coff, int CIN,
                           const int* __restrict__ idx, float* __restrict__ e,
                           int n0, int np){
  int W2 = 2*CIN;
  int i = blockIdx.x*256 + threadIdx.x;
  if (i >= np*KNN_K*W2) return;
  int c = i % W2; int ek = i / W2;
  int nl = ek / KNN_K, k = ek % KNN_K;
  int n = n0 + nl;
  int j = idx[n*KNN_K + k];
  float out;
  if (c < CIN) out = xf[(size_t)j*227 + coff + c] - xf[(size_t)n*227 + coff + c];
  else         out = xf[(size_t)n*227 + coff + (c-CIN)];
  e[(size_t)ek*W2 + c] = out;
}

__global__ void kmax_k(const float* __restrict__ e2, int C, float* __restrict__ f1,
                       int n0, int np){
  int i = blockIdx.x*256 + threadIdx.x;
  if (i >= np*C) return;
  int nl = i / C, c = i % C;
  float v = -1e30f;
  for (int k=0;k<KNN_K;k++) v = fmaxf(v, e2[((size_t)nl*KNN_K+k)*C + c]);
  f1[(size_t)(n0+nl)*C + c] = v;
}

template<int C>
__global__ __launch_bounds__(256) void reduce1_k(const float* __restrict__ X, int n,
                                                 float* __restrict__ pmax, float* __restrict__ psum){
  const int tid = threadIdx.x;
  const int c = tid % C;
  const int r0 = tid / C;
  const int TPR = 256 / C;
  float vmax = -1e30f, vsum = 0.f;
  for (int row = blockIdx.x * TPR + r0; row < n; row += gridDim.x * TPR) {
    float v = X[(size_t)row * C + c];
    vmax = fmaxf(vmax, v); vsum += v;
  }
  __shared__ float smax[256], ssum[256];
  smax[tid]=vmax; ssum[tid]=vsum;
  __syncthreads();
  if (tid < C) {
    for (int q=1;q<TPR;q++){ vmax=fmaxf(vmax, smax[q*C+c]); vsum += ssum[q*C+c]; }
    pmax[blockIdx.x*C + c] = vmax; psum[blockIdx.x*C + c] = vsum;
  }
}

template<int C>
__global__ void reduce2_k(const float* __restrict__ pmax, const float* __restrict__ psum,
                          int nblk, float invn, float* __restrict__ fmaxo, float* __restrict__ favgo){
  int c = threadIdx.x; if (c >= C) return;
  float vmax=-1e30f, vsum=0.f;
  for (int b=0;b<nblk;b++){ vmax=fmaxf(vmax,pmax[b*C+c]); vsum+=psum[b*C+c]; }
  fmaxo[c]=vmax; favgo[c]=vsum*invn;
}

__global__ void concat_k(const float* __restrict__ xf, int coff, int CF,
                         const float* __restrict__ f1, int C,
                         const float* __restrict__ fmax, const float* __restrict__ favg,
                         float* __restrict__ h, int n0, int np){
  int W = CF + 3*C;
  int i = blockIdx.x*256 + threadIdx.x;
  if (i >= np*W) return;
  int nl = i / W, c = i % W;
  int n = n0 + nl;
  float v;
  if (c < CF)          v = xf[(size_t)n*227 + coff + c];
  else if (c < CF+C)   v = f1[(size_t)n*C + (c-CF)];
  else if (c < CF+2*C) v = fmax[c-CF-C];
  else                 v = favg[c-CF-2*C];
  h[(size_t)nl*W + c] = v;
}

__global__ void norms_k(const float* __restrict__ xf, float* __restrict__ nr){
  int n = blockIdx.x*256 + threadIdx.x;
  if (n >= N_PTS) return;
  const float* p = xf + (size_t)n*227 + 35;
  float s = 0.f;
  for (int d=0;d<64;d++) s += p[d]*p[d];
  nr[n] = s;
}

__global__ __launch_bounds__(64) void softgather_k(const float* __restrict__ logits,
                                                   const int* __restrict__ up_idx,
                                                   const float* __restrict__ xf,
                                                   float* __restrict__ z){
  __shared__ float lw[KUP]; __shared__ int li[KUP];
  int m = blockIdx.x;
  int tid = threadIdx.x;
  if (tid < KUP){ lw[tid] = logits[(size_t)m*KUP + tid]; li[tid] = up_idx[(size_t)m*KUP + tid]; }
  __syncthreads();
  float mx = -1e30f;
  for (int k=0;k<KUP;k++) mx = fmaxf(mx, lw[k]);
  __syncthreads();
  if (tid < KUP) lw[tid] = expf(lw[tid]-mx);
  __syncthreads();
  float s = 0.f;
  for (int k=0;k<KUP;k++) s += lw[k];
  float inv = 1.f/s;
  for (int c = tid; c < 227; c += 64){
    float acc = 0.f;
    for (int k=0;k<KUP;k++) acc += lw[k] * xf[(size_t)li[k]*227 + c];
    z[(size_t)m*227 + c] = acc*inv;
  }
}

// ---------------------------------------------------------------------------
extern "C" void kernel_launch(void* const* d_in, const int* in_sizes, int n_in,
                              void* d_out, int out_size, void* d_ws, size_t ws_size,
                              hipStream_t stream) {
  const int *idx0  = (const int*)d_in[3];
  const int *upidx = (const int*)d_in[37];

  // ---- workspace layout (floats) ----
  float* ws = (float*)d_ws;
  float* x_feat = ws;                     // [N,227]
  float* f1b    = ws + 3602944;           // [N,128]
  float* pmax   = ws + 5634560;
  float* psum   = ws + 5667328;
  float* fmaxv  = ws + 5700096;
  float* favgv  = ws + 5700224;
  int*   flag   = (int*)(ws + 5700352);
  int*   idx1   = (int*)(ws + 5700368);   // N*5
  float* nrm    = ws + 5779728;           // N
  float* logits = ws + 5795600;           // UP_ROWS
  float* wcvt   = ws + 6508352;           // 706,020 fp32 weights
  float* S      = ws + 7214400;           // scratch arena (9,662,464 floats)
  ushort_t* whi  = (ushort_t*)(S + 9662464);  // siren planes (114688 each)
  ushort_t* wlo  = whi + 114688;
  ushort_t* gwhi = wlo + 114688;              // mlp planes (196608 each)
  ushort_t* gwlo = gwhi + 196608;

  const size_t NEED = (size_t)(7214400 + 9662464) * 4
                    + (size_t)(114688*2 + 196608*2) * 2;   // ~68.8 MB
  if (ws_size < NEED) {
    fillmark_k<<<CDIV(out_size,256),256,0,stream>>>((bf16*)d_out, out_size);
    return;
  }

  // ---- dtype flag + one-shot weight conversion to fp32 ----
  flag_k<<<1,64,0,stream>>>((const uint*)d_in[2], flag);
  CvtTab tab;
  int wcoff = 0, seg = 0;
  auto CVT = [&](int i, int n)->const float* {
    tab.src[seg] = d_in[i]; tab.start[seg] = wcoff; seg++;
    const float* p = wcvt + wcoff; wcoff += n;
    return p;
  };
  const float *E0W1=CVT(4,8960),  *E0S1=CVT(5,128),  *E0H1=CVT(6,128),
              *E0W2=CVT(7,8192),  *E0B2=CVT(8,64);
  const float *F0W1=CVT(9,43584), *F0S1=CVT(10,192), *F0H1=CVT(11,192),
              *F0W2=CVT(12,24576),*F0S2=CVT(13,128), *F0H2=CVT(14,128),
              *F0W3=CVT(15,8192), *F0S3=CVT(16,64),  *F0H3=CVT(17,64),
              *F0W4=CVT(18,4096), *F0B4=CVT(19,64);
  const float *E1W1=CVT(20,32768),*E1S1=CVT(21,256), *E1H1=CVT(22,256),
              *E1W2=CVT(23,32768),*E1B2=CVT(24,128);
  const float *F1W1=CVT(25,172032),*F1S1=CVT(26,384),*F1H1=CVT(27,384),
              *F1W2=CVT(28,98304),*F1S2=CVT(29,256), *F1H2=CVT(30,256),
              *F1W3=CVT(31,32768),*F1S3=CVT(32,128), *F1H3=CVT(33,128),
              *F1W4=CVT(34,16384),*F1B4=CVT(35,128);
  const float *UPW0=CVT(38,896),  *UPS0=CVT(39,128), *UPH0=CVT(40,128),
              *UPWR=CVT(41,114688),*UPSR=CVT(42,896),*UPHR=CVT(43,896),
              *UPWF=CVT(44,128),  *UPBF=CVT(45,1);
  const float *DW0=CVT(46,58112), *DB0=CVT(47,256),
              *DW1=CVT(48,32768), *DB1=CVT(49,128),
              *DW2=CVT(50,8192),  *DB2=CVT(51,64),
              *DW3=CVT(52,2048),  *DB3=CVT(53,32),
              *DW4=CVT(54,512),   *DB4=CVT(55,16),
              *DWF=CVT(56,48),    *DBF=CVT(57,3);
  cvt_all_k<<<CDIV(wcoff,256),256,0,stream>>>(tab, wcvt, flag, wcoff);

  // siren planes
  packfrag_k<<<CDIV(114688,256),256,0,stream>>>(UPWR, whi, wlo, 114688);

  // mlp planes (fc0 + decoder, incl. head)
  int offs[10]; const float* srcs[10]; int Ns[10], Ks[10], Kps[10];
  {
    int o = 0, q = 0;
    auto REG = [&](const float* s, int N, int K, int Kpad){
      srcs[q]=s; Ns[q]=N; Ks[q]=K; Kps[q]=Kpad; offs[q]=o;
      o += CDIV(N,32)*32*Kpad; q++;
    };
    REG(F0W1,192,227,256); REG(F0W2,128,192,192); REG(F0W3,64,128,128); REG(F0W4,64,64,64);
    REG(DW0,256,227,256);  REG(DW1,128,256,256);  REG(DW2,64,128,128);
    REG(DW3,32,64,64);     REG(DW4,16,32,32);     REG(DWF,3,16,32);
  }
  for (int q = 0; q < 10; q++){
    int total = CDIV(Ns[q],32)*32*Kps[q];
    packw_mfma_k<<<CDIV(total,256),256,0,stream>>>(srcs[q], gwhi+offs[q], gwlo+offs[q],
                                                   Ns[q], Ks[q], Kps[q], total);
  }

  auto OFF = [&](const float* p){ return (int)(p - wcvt); };
  MCfg cfc0{};
  cfc0.L[0] = {227,192,8,6, offs[0], OFF(F0S1), OFF(F0H1), 0,1, 0.f};
  cfc0.L[1] = {192,128,6,4, offs[1], OFF(F0S2), OFF(F0H2), 0,1, 0.f};
  cfc0.L[2] = {128, 64,4,2, offs[2], OFF(F0S3), OFF(F0H3), 0,1, 0.f};
  cfc0.L[3] = { 64, 64,2,2, offs[3], 0,         OFF(F0B4), 1,0, 0.f};
  MCfg cdec{};
  cdec.L[0] = {227,256,8,8, offs[4], 0, OFF(DB0), 2,2, 30.f};
  cdec.L[1] = {256,128,8,4, offs[5], 0, OFF(DB1), 1,2, 0.f};
  cdec.L[2] = {128, 64,4,2, offs[6], 0, OFF(DB2), 1,2, 0.f};
  cdec.L[3] = { 64, 32,2,1, offs[7], 0, OFF(DB3), 1,2, 0.f};
  cdec.L[4] = { 32, 16,1,1, offs[8], 0, OFF(DB4), 1,2, 0.f};
  cdec.L[5] = { 16,  3,1,1, offs[9], 0, OFF(DBF), 1,0, 0.f};

  const float invN = 1.f/(float)N_PTS;
  const int CHP = 3072;    // edge-phase point chunk
  const int CHN = 8192;    // fc1-phase row chunk

  featin_k<<<CDIV(N_PTS*35,256),256,0,stream>>>(d_in[1], d_in[2], x_feat, flag);

  // ---- phase 1: emb block 0 (edge conv: fp32 gemm_k, round-7 proven)
  for (int n0 = 0; n0 < N_PTS; n0 += CHP) {
    int np = N_PTS - n0; if (np > CHP) np = CHP;
    int ne = np * KNN_K;
    float* eA = S;
    float* eB = S + 1075200;
    gather_e_k<<<CDIV(ne*70,256),256,0,stream>>>(x_feat, 0, 35, idx0, eA, n0, np);
    gemm_k<0,1><<<dim3(CDIV(ne,64),2),256,0,stream>>>(eA,70, E0W1,70, E0S1,E0H1,0.f, eB,128, ne,128,70);
    gemm_k<1,0><<<dim3(CDIV(ne,64),1),256,0,stream>>>(eB,128, E0W2,128, nullptr,E0B2,0.f, eA,64, ne,64,128);
    kmax_k<<<CDIV(np*64,256),256,0,stream>>>(eA, 64, f1b, n0, np);
  }
  reduce1_k<64><<<256,256,0,stream>>>(f1b, N_PTS, pmax, psum);
  reduce2_k<64><<<1,64,0,stream>>>(pmax, psum, 256, invN, fmaxv, favgv);
  // fc0: full concat then ONE fused MLP
  {
    float* h = S;   // [N,227]
    concat_k<<<CDIV(N_PTS*227,256),256,0,stream>>>(x_feat,0,35, f1b,64, fmaxv,favgv, h, 0, N_PTS);
    mlp_fused_k<4,0><<<CDIV(N_PTS,64),256,0,stream>>>(
        h,227,227,N_PTS, cfc0, gwhi,gwlo,wcvt, x_feat+35,227, nullptr, flag);
  }

  // ---- phase 2: dynamic KNN (MFMA)
  norms_k<<<CDIV(N_PTS,256),256,0,stream>>>(x_feat, nrm);
  {
    const int PLANE = NTILE*5*64*8;
    ushort_t* ajhi = (ushort_t*)S;
    ushort_t* ajlo = ajhi + PLANE;
    ushort_t* bihi = ajlo + PLANE;
    ushort_t* bilo = bihi + PLANE;
    packknn_k<<<CDIV(PLANE,256),256,0,stream>>>(x_feat, nrm, ajhi, ajlo, bihi, bilo);
    knn_mfma_k<<<NTILE,256,0,stream>>>(ajhi, ajlo, bihi, bilo, idx1);
  }

  // ---- phase 3: emb block 1 (edge conv fp32 gemm_k; fc1 fp32 gemm_k)
  for (int n0 = 0; n0 < N_PTS; n0 += CHP) {
    int np = N_PTS - n0; if (np > CHP) np = CHP;
    int ne = np * KNN_K;
    float* eA = S;
    float* eB = S + 1966080;
    gather_e_k<<<CDIV(ne*128,256),256,0,stream>>>(x_feat, 35, 64, idx1, eA, n0, np);
    gemm_k<0,1><<<dim3(CDIV(ne,64),4),256,0,stream>>>(eA,128, E1W1,128, E1S1,E1H1,0.f, eB,256, ne,256,128);
    gemm_k<1,0><<<dim3(CDIV(ne,64),2),256,0,stream>>>(eB,256, E1W2,256, nullptr,E1B2,0.f, eA,128, ne,128,256);
    kmax_k<<<CDIV(np*128,256),256,0,stream>>>(eA, 128, f1b, n0, np);
  }
  reduce1_k<128><<<256,256,0,stream>>>(f1b, N_PTS, pmax, psum);
  reduce2_k<128><<<1,128,0,stream>>>(pmax, psum, 256, invN, fmaxv, favgv);
  for (int n0 = 0; n0 < N_PTS; n0 += CHN) {
    int np = N_PTS - n0; if (np > CHN) np = CHN;
    float* h  = S;
    float* a1 = S + 3670016;
    int gx = CDIV(np,64);
    concat_k<<<CDIV(np*448,256),256,0,stream>>>(x_feat,35,64, f1b,128, fmaxv,favgv, h, n0, np);
    gemm_k<0,1><<<dim3(gx,6),256,0,stream>>>(h,448,  F1W1,448, F1S1,F1H1,0.f, a1,384, np,384,448);
    gemm_k<0,1><<<dim3(gx,4),256,0,stream>>>(a1,384, F1W2,384, F1S2,F1H2,0.f, h,256,  np,256,384);
    gemm_k<0,1><<<dim3(gx,2),256,0,stream>>>(h,256,  F1W3,256, F1S3,F1H3,0.f, a1,128, np,128,256);
    gemm_k<1,0><<<dim3(gx,2),256,0,stream>>>(a1,128, F1W4,128, nullptr,F1B4,0.f, x_feat+(size_t)n0*227+99,227, np,128,128);
  }

  // ---- phase 4: fused SIREN -> logits; softmax gather -> z
  siren_fused_k<<<CDIV(UP_ROWS,128),256,0,stream>>>(
      d_in[36], whi, wlo, UPW0, UPS0, UPH0, UPSR, UPHR, UPWF, UPBF, logits, flag);
  float* zbuf = S;                 // [M,227]
  softgather_k<<<M_PTS,64,0,stream>>>(logits, upidx, x_feat, zbuf);

  // ---- phase 5: SIREN decoder: ONE fused MLP (incl. 16->3 head + output)
  mlp_fused_k<6,1><<<CDIV(M_PTS,64),256,0,stream>>>(
      zbuf,227,227,M_PTS, cdec, gwhi,gwlo,wcvt, nullptr,0, d_out, flag);
}

// Round 11
// 2303.341 us; speedup vs baseline: 1.5423x; 1.0462x over previous
//
#include <hip/hip_runtime.h>
#include <hip/hip_bf16.h>
#include <math.h>

#define N_PTS 15872
#define M_PTS 35637
#define KNN_K 5
#define KUP   20
#define UP_ROWS (M_PTS * KUP)   // 712740
#define NTILE (N_PTS/32)        // 496 i/j tiles
#define CDIV(a,b) (((a)+(b)-1)/(b))

typedef __hip_bfloat16 bf16;
typedef unsigned int uint;
typedef unsigned short ushort_t;
__device__ __forceinline__ float b2f(bf16 x){ return __bfloat162float(x); }

// round-to-nearest-even fp32 -> bf16 bit pattern (finite inputs)
__device__ __forceinline__ uint f2bf_bits(float x){
  uint u = __float_as_uint(x);
  return (u + 0x7FFFu + ((u>>16)&1u)) >> 16;
}

typedef __attribute__((ext_vector_type(8))) short bf16x8;
typedef __attribute__((ext_vector_type(16))) float f32x16;
union FragAB { bf16x8 v; uint u[4]; };
union FragB  { bf16x8 v; uint4 q; };
union Acc16  { f32x16 v; float f[16]; };

// ---------------------------------------------------------------------------
__global__ void flag_k(const uint* __restrict__ pos_raw, int* __restrict__ flag){
  if (threadIdx.x == 0 && blockIdx.x == 0)
    flag[0] = (pos_raw[0] == 0x3F800000u) ? 1 : 0;
}

struct CvtTab { const void* src[52]; int start[52]; };
__global__ __launch_bounds__(256) void cvt_all_k(CvtTab tab, float* __restrict__ dst,
                                                 const int* __restrict__ flag, int total){
  int i = blockIdx.x*256 + threadIdx.x;
  if (i >= total) return;
  int s = 0;
#pragma unroll 1
  for (int k = 1; k < 52; k++) if (tab.start[k] <= i) s = k;
  int off = i - tab.start[s];
  float v = flag[0] ? b2f(((const bf16*)tab.src[s])[off]) : ((const float*)tab.src[s])[off];
  dst[i] = v;
}

// pack SIREN 128x128 weights into frag-major split-bf16 hi/lo planes.
__global__ void packfrag_k(const float* __restrict__ w, ushort_t* __restrict__ whi,
                           ushort_t* __restrict__ wlo, int n){
  int i = blockIdx.x*256 + threadIdx.x;
  if (i >= n) return;
  int j = i & 7;
  int lam = (i >> 3) & 63;
  int fg = i >> 9;
  int t = fg & 3, ks = (fg >> 2) & 1, Q = (fg >> 3) & 3, l = fg >> 5;
  int nn = t*32 + (lam & 31);
  int kk = Q*32 + ks*16 + (lam >> 5)*8 + j;
  float x = w[l*16384 + nn*128 + kk];
  uint hb = f2bf_bits(x);
  uint lb = f2bf_bits(x - __uint_as_float(hb << 16));
  whi[i] = (ushort_t)hb;
  wlo[i] = (ushort_t)lb;
}

// generic frag-major split-bf16 pack for weight matrix W[N][K] (row-major),
// K padded to Kpad (x32), N padded to x32 with zeros.
__global__ void packw_mfma_k(const float* __restrict__ w, ushort_t* __restrict__ whi,
                             ushort_t* __restrict__ wlo, int N, int K, int Kpad, int total){
  int i = blockIdx.x*256 + threadIdx.x;
  if (i >= total) return;
  int j = i & 7;
  int lane = (i >> 3) & 63;
  int fr = i >> 9;
  int nq = Kpad >> 5;
  int ks = fr & 1;
  int q  = (fr >> 1) % nq;
  int nt = (fr >> 1) / nq;
  int n = nt*32 + (lane & 31);
  int k = q*32 + ks*16 + (lane >> 5)*8 + j;
  float x = (n < N && k < K) ? w[(size_t)n*K + k] : 0.f;
  uint hb = f2bf_bits(x);
  uint lb = f2bf_bits(x - __uint_as_float(hb << 16));
  whi[i] = (ushort_t)hb;
  wlo[i] = (ushort_t)lb;
}

// pack KNN features into frag-major split-bf16 planes with norm augmentation.
__global__ void packknn_k(const float* __restrict__ xf, const float* __restrict__ nr,
                          ushort_t* __restrict__ ahi, ushort_t* __restrict__ alo,
                          ushort_t* __restrict__ bhi, ushort_t* __restrict__ blo){
  int i = blockIdx.x*256 + threadIdx.x;
  if (i >= NTILE*5*64*8) return;
  int e = i & 7;
  int lane = (i >> 3) & 63;
  int rest = i >> 9;
  int kc = rest % 5, jt = rest / 5;
  int n = jt*32 + (lane & 31);
  int k = kc*16 + (lane >> 5)*8 + e;
  float f = (k < 64) ? xf[(size_t)n*227 + 35 + k] : 0.f;
  float av, bv;
  if (k < 64)      { av = 2.f*f;   bv = f; }
  else if (k == 64){ av = nr[n];   bv = -1.f; }
  else if (k == 65){ av = 1.f;     bv = -nr[n]; }
  else             { av = 0.f;     bv = 0.f; }
  uint ah = f2bf_bits(av); uint al = f2bf_bits(av - __uint_as_float(ah<<16));
  uint bh = f2bf_bits(bv); uint bl = f2bf_bits(bv - __uint_as_float(bh<<16));
  ahi[i] = (ushort_t)ah; alo[i] = (ushort_t)al;
  bhi[i] = (ushort_t)bh; blo[i] = (ushort_t)bl;
}

__global__ void fillmark_k(bf16* __restrict__ out, int n){
  int i = blockIdx.x*256 + threadIdx.x;
  if (i < n) out[i] = __float2bfloat16(12345.0f);
}

// ---------------------------------------------------------------------------
// fp32 fused GEMM (round-7 proven; used for edge + fc1 stacks)
// ---------------------------------------------------------------------------
template<int EPI, int ACT>
__global__ __launch_bounds__(256) void gemm_k(
    const float* __restrict__ A, int lda,
    const float* __restrict__ W, int ldw,
    const float* __restrict__ scale, const float* __restrict__ shift,
    float gmul, float* __restrict__ C, int ldc,
    int M, int Nout, int K)
{
  __shared__ __align__(16) float As[16][64];
  __shared__ __align__(16) float Ws[16][64];
  const int tid = threadIdx.x;
  const int tx = tid & 15, ty = tid >> 4;
  const int bm = blockIdx.x * 64, bn = blockIdx.y * 64;
  const int ar = tid >> 2, ak = (tid & 3) * 4;
  float acc[4][4] = {};
  for (int k0 = 0; k0 < K; k0 += 16) {
    float a0=0.f,a1=0.f,a2=0.f,a3=0.f;
    int grow = bm + ar;
    if (grow < M) {
      const float* ap = A + (size_t)grow * lda + (k0 + ak);
      int rem = K - (k0 + ak);
      if (rem >= 4) { a0=ap[0]; a1=ap[1]; a2=ap[2]; a3=ap[3]; }
      else { if(rem>0)a0=ap[0]; if(rem>1)a1=ap[1]; if(rem>2)a2=ap[2]; }
    }
    float w0=0.f,w1=0.f,w2=0.f,w3=0.f;
    int gn = bn + ar;
    if (gn < Nout) {
      const float* wp = W + (size_t)gn * ldw + (k0 + ak);
      int rem = K - (k0 + ak);
      if (rem >= 4) { w0=wp[0]; w1=wp[1]; w2=wp[2]; w3=wp[3]; }
      else { if(rem>0)w0=wp[0]; if(rem>1)w1=wp[1]; if(rem>2)w2=wp[2]; }
    }
    __syncthreads();
    As[ak+0][ar]=a0; As[ak+1][ar]=a1; As[ak+2][ar]=a2; As[ak+3][ar]=a3;
    Ws[ak+0][ar]=w0; Ws[ak+1][ar]=w1; Ws[ak+2][ar]=w2; Ws[ak+3][ar]=w3;
    __syncthreads();
#pragma unroll
    for (int kk = 0; kk < 16; kk++) {
      float4 av = *reinterpret_cast<const float4*>(&As[kk][ty*4]);
      float4 wv = *reinterpret_cast<const float4*>(&Ws[kk][tx*4]);
      float aa[4] = {av.x,av.y,av.z,av.w};
      float ww[4] = {wv.x,wv.y,wv.z,wv.w};
#pragma unroll
      for (int i=0;i<4;i++)
#pragma unroll
        for (int j=0;j<4;j++) acc[i][j] += aa[i]*ww[j];
    }
  }
#pragma unroll
  for (int i=0;i<4;i++){
    int m = bm + ty*4 + i;
    if (m >= M) continue;
#pragma unroll
    for (int j=0;j<4;j++){
      int n = bn + tx*4 + j;
      if (n >= Nout) continue;
      float v = acc[i][j];
      if (EPI==0)      v = v * scale[n] + shift[n];
      else if (EPI==1) v = v + shift[n];
      else             v = (v + shift[n]) * gmul;
      if (ACT==1)      v = v > 0.f ? v : 0.2f*v;
      else if (ACT==2) v = sinf(v);
      C[(size_t)m*ldc + n] = v;
    }
  }
}

// ---------------------------------------------------------------------------
// Generic fused per-row MLP (validated round 9): up to 6 layers, dims <= 256.
// Block 256 = 4 waves: wave = (row-half, tile-half). 64 rows/block.
// Activations packed split-bf16 u32 in swizzled LDS slab [64][256].
// OUTMODE 0: final layer -> fp32 Cout[row*ldc+col].
// OUTMODE 1: final layer -> flagged bf16/fp32 at oflg[row*3+col] (canary).
// ---------------------------------------------------------------------------
struct MLayer { int K, N, Kq, Nt, woff, soff, hoff, epi, act; float gmul; };
struct MCfg { MLayer L[6]; };

template<int NL, int OUTMODE>
__global__ __launch_bounds__(256) void mlp_fused_k(
    const float* __restrict__ A0, int lda0, int K0, int M,
    MCfg cfg,
    const ushort_t* __restrict__ wh, const ushort_t* __restrict__ wl,
    const float* __restrict__ wc,
    float* __restrict__ Cout, int ldc,
    void* __restrict__ oflg, const int* __restrict__ flag)
{
  __shared__ __align__(16) uint slab[64*256];   // 65536 B
  const int tid = threadIdx.x;
  const int lane = tid & 63;
  const int wv = tid >> 6;
  const int np = lane & 31;
  const int hb2 = lane >> 5;
  const int rhalf = wv & 1, thalf = wv >> 1;
  const int rb = blockIdx.x * 64;
  const int row_l = rhalf*32 + np;

  for (int e = tid; e < 64*64; e += 256) {
    int r = e >> 6, g = e & 63;
    int gr = rb + r;
    uint p[4];
#pragma unroll
    for (int u=0;u<4;u++){
      int k = g*4+u;
      float f = (gr < M && k < K0) ? A0[(size_t)gr*lda0 + k] : 0.f;
      uint hb = f2bf_bits(f);
      uint lb = f2bf_bits(f - __uint_as_float(hb<<16));
      p[u] = (hb<<16) | lb;
    }
    *(uint4*)&slab[r*256 + (((g ^ r) & 63)<<2)] = make_uint4(p[0],p[1],p[2],p[3]);
  }
  __syncthreads();

#pragma unroll 1
  for (int l = 0; l < NL; l++){
    const int N = cfg.L[l].N, Kq = cfg.L[l].Kq, Nt = cfg.L[l].Nt;
    const int woff = cfg.L[l].woff, soff = cfg.L[l].soff, hoff = cfg.L[l].hoff;
    const int epi = cfg.L[l].epi, actf = cfg.L[l].act;
    const float gmul = cfg.L[l].gmul;
    Acc16 acc[4];
#pragma unroll
    for (int u=0;u<4;u++)
#pragma unroll
      for (int i=0;i<16;i++) acc[u].f[i] = 0.f;

#pragma unroll 1
    for (int q = 0; q < Kq; q++){
#pragma unroll
      for (int ks = 0; ks < 2; ks++){
        int g0 = (q*32 + ks*16 + hb2*8) >> 2;
        uint4 a0 = *(const uint4*)&slab[row_l*256 + ((((g0  ) ^ row_l) & 63)<<2)];
        uint4 a1 = *(const uint4*)&slab[row_l*256 + ((((g0+1) ^ row_l) & 63)<<2)];
        uint au[8] = {a0.x,a0.y,a0.z,a0.w,a1.x,a1.y,a1.z,a1.w};
        FragAB ah, al;
#pragma unroll
        for (int p=0;p<4;p++){
          ah.u[p] = (au[2*p]>>16)     | (au[2*p+1] & 0xFFFF0000u);
          al.u[p] = (au[2*p]&0xFFFFu) | (au[2*p+1]<<16);
        }
#pragma unroll
        for (int u=0;u<4;u++){
          int t = thalf + u*2;
          if (t < Nt){
            size_t fb = (size_t)woff + ((size_t)((t*Kq + q)*2 + ks))*512 + (size_t)lane*8;
            FragB bh, bl;
            bh.q = *(const uint4*)(wh + fb);
            bl.q = *(const uint4*)(wl + fb);
            acc[u].v = __builtin_amdgcn_mfma_f32_32x32x16_bf16(ah.v, bh.v, acc[u].v, 0,0,0);
            acc[u].v = __builtin_amdgcn_mfma_f32_32x32x16_bf16(al.v, bh.v, acc[u].v, 0,0,0);
            acc[u].v = __builtin_amdgcn_mfma_f32_32x32x16_bf16(ah.v, bl.v, acc[u].v, 0,0,0);
          }
        }
      }
    }
    __syncthreads();
#pragma unroll
    for (int u=0;u<4;u++){
      int t = thalf + u*2;
      if (t < Nt){
        int col = t*32 + np;
        if (col < N){
          float scv = (epi==0) ? wc[soff+col] : 0.f;
          float shv = wc[hoff+col];
#pragma unroll
          for (int reg=0;reg<16;reg++){
            int r32 = (reg&3) + 8*(reg>>2) + 4*hb2;
            float v = acc[u].f[reg];
            if (epi==0)      v = v*scv + shv;
            else if (epi==1) v = v + shv;
            else             v = (v + shv)*gmul;
            if (actf==1)      v = v > 0.f ? v : 0.2f*v;
            else if (actf==2) v = __sinf(v);
            if (l == NL-1){
              int gr = rb + rhalf*32 + r32;
              if (gr < M){
                if (OUTMODE==0) Cout[(size_t)gr*ldc + col] = v;
                else {
                  if (!(fabsf(v) < 1e30f)) v = 777.0f;  // canary
                  size_t oi = (size_t)gr*3 + col;
                  if (flag[0]) ((bf16*)oflg)[oi] = __float2bfloat16(v);
                  else         ((float*)oflg)[oi] = v;
                }
              }
            } else {
              int r = rhalf*32 + r32;
              uint hb = f2bf_bits(v);
              uint lb = f2bf_bits(v - __uint_as_float(hb<<16));
              slab[r*256 + ((((col>>2) ^ r) & 63)<<2) + (col&3)] = (hb<<16) | lb;
            }
          }
        }
      }
    }
    __syncthreads();
  }
}

// ---------------------------------------------------------------------------
// MFMA KNN (validated round 7).
// ---------------------------------------------------------------------------
#define INS5(tv, tj, v, j) \
  if ((v) > tv[4]){ tv[4]=(v); tj[4]=(j); \
    _Pragma("unroll") \
    for (int q=4;q>0;q--) \
      if (tv[q] > tv[q-1]){ float tf=tv[q-1]; tv[q-1]=tv[q]; tv[q]=tf; \
                            int ti=tj[q-1]; tj[q-1]=tj[q]; tj[q]=ti; } }

__global__ __launch_bounds__(256) void knn_mfma_k(
    const ushort_t* __restrict__ ahi, const ushort_t* __restrict__ alo,
    const ushort_t* __restrict__ bhi, const ushort_t* __restrict__ blo,
    int* __restrict__ out)
{
  __shared__ float mv[4][32][5];
  __shared__ int   mjj[4][32][5];
  const int tid = threadIdx.x;
  const int lane = tid & 63;
  const int wv = tid >> 6;
  const int np = lane & 31;
  const int hb2 = lane >> 5;
  const int it = blockIdx.x;
  const int ig = it*32 + np;

  FragB vh[5], vl[5];
  {
    size_t bb = (size_t)(it*5)*512 + (size_t)lane*8;
#pragma unroll
    for (int kc=0;kc<5;kc++){
      vh[kc].q = *(const uint4*)(bhi + bb + kc*512);
      vl[kc].q = *(const uint4*)(blo + bb + kc*512);
    }
  }

  float tv[5] = {-1e30f,-1e30f,-1e30f,-1e30f,-1e30f};
  int   tj[5] = {0,0,0,0,0};

  FragB uh[5], ul[5], nh[5], nl[5];
  {
    size_t ab = (size_t)(wv*5)*512 + (size_t)lane*8;
#pragma unroll
    for (int kc=0;kc<5;kc++){
      uh[kc].q = *(const uint4*)(ahi + ab + kc*512);
      ul[kc].q = *(const uint4*)(alo + ab + kc*512);
    }
  }

#pragma unroll 1
  for (int t = 0; t < NTILE/4; t++){
    int jt = wv + t*4;
    if (t+1 < NTILE/4){
      size_t an = (size_t)((jt+4)*5)*512 + (size_t)lane*8;
#pragma unroll
      for (int kc=0;kc<5;kc++){
        nh[kc].q = *(const uint4*)(ahi + an + kc*512);
        nl[kc].q = *(const uint4*)(alo + an + kc*512);
      }
    }
    Acc16 acc;
#pragma unroll
    for (int q=0;q<16;q++) acc.f[q] = 0.f;
#pragma unroll
    for (int kc=0;kc<5;kc++){
      acc.v = __builtin_amdgcn_mfma_f32_32x32x16_bf16(uh[kc].v, vh[kc].v, acc.v, 0,0,0);
      acc.v = __builtin_amdgcn_mfma_f32_32x32x16_bf16(ul[kc].v, vh[kc].v, acc.v, 0,0,0);
      acc.v = __builtin_amdgcn_mfma_f32_32x32x16_bf16(uh[kc].v, vl[kc].v, acc.v, 0,0,0);
    }
    int jb = jt*32 + 4*hb2;
#pragma unroll
    for (int reg=0;reg<16;reg++){
      int j = jb + (reg&3) + 8*(reg>>2);
      float v = acc.f[reg];
      if (j != ig) { INS5(tv, tj, v, j); }
    }
    if (t+1 < NTILE/4){
#pragma unroll
      for (int kc=0;kc<5;kc++){ uh[kc] = nh[kc]; ul[kc] = nl[kc]; }
    }
  }

#pragma unroll
  for (int s=0;s<5;s++){
    float ov = __shfl_xor(tv[s], 32, 64);
    int   oj = __shfl_xor(tj[s], 32, 64);
    INS5(tv, tj, ov, oj);
  }
  if (hb2 == 0){
#pragma unroll
    for (int s=0;s<5;s++){ mv[wv][np][s] = tv[s]; mjj[wv][np][s] = tj[s]; }
  }
  __syncthreads();
  if (tid < 32){
    float bv[5]; int bj[5];
#pragma unroll
    for (int s=0;s<5;s++){ bv[s] = mv[0][tid][s]; bj[s] = mjj[0][tid][s]; }
#pragma unroll
    for (int w=1;w<4;w++)
#pragma unroll
      for (int s=0;s<5;s++){
        float v = mv[w][tid][s]; int j = mjj[w][tid][s];
        INS5(bv, bj, v, j);
      }
    int gi = it*32 + tid;
#pragma unroll
    for (int s=0;s<5;s++) out[gi*KNN_K + s] = bj[s];
  }
}

// ---------------------------------------------------------------------------
// Fused 8-layer SIREN + head. v3: wave-private act slab -> NO per-layer
// barriers (only the initial staging barrier); truncation-split hi.
// ---------------------------------------------------------------------------
__global__ __launch_bounds__(256, 2) void siren_fused_k(
    const void* __restrict__ upin,
    const ushort_t* __restrict__ whi, const ushort_t* __restrict__ wlo,
    const float* __restrict__ W0c, const float* __restrict__ S0c, const float* __restrict__ H0c,
    const float* __restrict__ SRc, const float* __restrict__ HRc,
    const float* __restrict__ WFc, const float* __restrict__ BFc,
    float* __restrict__ logits, const int* __restrict__ flag)
{
  __shared__ __align__(16) uint act[4*32*128];
  __shared__ float intile[4*32*8];
  __shared__ float w0s[128*9];
  __shared__ float wfs[128];
  __shared__ float bfs[1];

  const int tid  = threadIdx.x;
  const int lane = tid & 63;
  const int wv   = tid >> 6;
  const int np   = lane & 31;
  const int hb2  = lane >> 5;
  const int rowbase = blockIdx.x * 128 + wv * 32;
  const int isbf = flag[0];
  uint*  actw = act + wv*32*128;
  float* intw = intile + wv*32*8;

  for (int e = tid; e < 128*7; e += 256) w0s[(e/7)*9 + (e%7)] = W0c[e];
  if (tid < 128) wfs[tid] = WFc[tid];
  if (tid == 0) bfs[0] = BFc[0];
  for (int e = lane; e < 32*7; e += 64) {
    int r = e/7, k = e%7;
    int gr = rowbase + r;
    float v = 0.f;
    if (gr < UP_ROWS)
      v = isbf ? b2f(((const bf16*)upin)[(size_t)gr*7+k]) : ((const float*)upin)[(size_t)gr*7+k];
    intw[r*8+k] = v;
  }
  __syncthreads();   // block-shared staging (w0s/wfs/bfs) -- must stay

#pragma unroll
  for (int t = 0; t < 4; t++) {
    int c = t*32 + np;
    float s = S0c[c], b = H0c[c];
#pragma unroll
    for (int reg = 0; reg < 16; reg++) {
      int r = (reg&3) + 8*(reg>>2) + 4*hb2;
      float a = 0.f;
#pragma unroll
      for (int k = 0; k < 7; k++) a += intw[r*8+k]*w0s[c*9+k];
      float x = __sinf(a*s + b);
      uint xu = __float_as_uint(x);
      uint hbi = xu >> 16;                               // trunc hi
      uint lbi = f2bf_bits(x - __uint_as_float(hbi<<16)); // RNE residual
      int col = (c & 3) | ((((c>>2) ^ r) & 31) << 2);
      actw[r*128 + col] = (hbi<<16) | lbi;
    }
  }

  // layers 1..7: act slab is wave-private -> no __syncthreads needed
#pragma unroll 1
  for (int l = 0; l < 7; l++) {
    float sc[4], sh[4];
#pragma unroll
    for (int t=0;t<4;t++){ sc[t] = SRc[l*128 + t*32 + np]; sh[t] = HRc[l*128 + t*32 + np]; }
    Acc16 acc[4];
#pragma unroll
    for (int t=0;t<4;t++)
#pragma unroll
      for (int i=0;i<16;i++) acc[t].f[i] = 0.f;

#pragma unroll 1
    for (int Q = 0; Q < 4; Q++) {
#pragma unroll
      for (int ks = 0; ks < 2; ks++) {
        int g0 = (Q*32 + ks*16 + hb2*8) >> 2;
        uint4 a0 = *(const uint4*)&actw[np*128 + ((g0 ^ np) << 2)];
        uint4 a1 = *(const uint4*)&actw[np*128 + (((g0+1) ^ np) << 2)];
        uint au[8] = {a0.x,a0.y,a0.z,a0.w,a1.x,a1.y,a1.z,a1.w};
        FragAB ahi, alo;
#pragma unroll
        for (int p=0;p<4;p++){
          ahi.u[p] = (au[2*p]>>16)     | (au[2*p+1] & 0xFFFF0000u);
          alo.u[p] = (au[2*p]&0xFFFFu) | (au[2*p+1]<<16);
        }
        size_t fb = ((size_t)(((l*4 + Q)*2 + ks)*4) << 9) + (size_t)lane*8;
        FragB bh[4], bl[4];
#pragma unroll
        for (int t=0;t<4;t++){
          bh[t].q = *(const uint4*)(whi + fb + (size_t)t*512);
          bl[t].q = *(const uint4*)(wlo + fb + (size_t)t*512);
        }
#pragma unroll
        for (int t=0;t<4;t++){
          acc[t].v = __builtin_amdgcn_mfma_f32_32x32x16_bf16(ahi.v, bh[t].v, acc[t].v, 0,0,0);
          acc[t].v = __builtin_amdgcn_mfma_f32_32x32x16_bf16(alo.v, bh[t].v, acc[t].v, 0,0,0);
          acc[t].v = __builtin_amdgcn_mfma_f32_32x32x16_bf16(ahi.v, bl[t].v, acc[t].v, 0,0,0);
        }
      }
    }
#pragma unroll
    for (int t=0;t<4;t++){
      int c = t*32 + np;
#pragma unroll
      for (int reg=0;reg<16;reg++){
        int r = (reg&3) + 8*(reg>>2) + 4*hb2;
        float x = __sinf(acc[t].f[reg]*sc[t] + sh[t]);
        uint xu = __float_as_uint(x);
        uint hbi = xu >> 16;
        uint lbi = f2bf_bits(x - __uint_as_float(hbi<<16));
        int col = (c & 3) | ((((c>>2) ^ r) & 31) << 2);
        actw[r*128 + col] = (hbi<<16) | lbi;
      }
    }
  }

  {
    float a = 0.f;
#pragma unroll
    for (int g = 0; g < 16; g++) {
      int gg = hb2*16 + g;
      uint4 u = *(const uint4*)&actw[np*128 + ((gg ^ np) << 2)];
      int kb = gg*4;
      float x0 = __uint_as_float(u.x & 0xFFFF0000u) + __uint_as_float(u.x<<16);
      float x1 = __uint_as_float(u.y & 0xFFFF0000u) + __uint_as_float(u.y<<16);
      float x2 = __uint_as_float(u.z & 0xFFFF0000u) + __uint_as_float(u.z<<16);
      float x3 = __uint_as_float(u.w & 0xFFFF0000u) + __uint_as_float(u.w<<16);
      a += x0*wfs[kb] + x1*wfs[kb+1] + x2*wfs[kb+2] + x3*wfs[kb+3];
    }
    a += __shfl_xor(a, 32, 64);
    int gr = rowbase + np;
    if (hb2 == 0 && gr < UP_ROWS) logits[gr] = a + bfs[0];
  }
}

// ---------------------------------------------------------------------------
__global__ void featin_k(const void* __restrict__ ldx, const void* __restrict__ pos,
                         float* __restrict__ xf, const int* __restrict__ flag){
  int i = blockIdx.x*256 + threadIdx.x;
  if (i >= N_PTS*35) return;
  int n = i / 35, c = i % 35;
  float v;
  if (flag[0]) {
    v = (c < 3) ? b2f(((const bf16*)ldx)[n*3+c]) : b2f(((const bf16*)pos)[n*32 + (c-3)]);
  } else {
    v = (c < 3) ? ((const float*)ldx)[n*3+c] : ((const float*)pos)[n*32 + (c-3)];
  }
  xf[(size_t)n*227 + c] = v;
}

__global__ void gather_e_k(const float* __restrict__ xf, int coff, int CIN,
                           const int* __restrict__ idx, float* __restrict__ e,
                           int n0, int np){
  int W2 = 2*CIN;
  int i = blockIdx.x*256 + threadIdx.x;
  if (i >= np*KNN_K*W2) return;
  int c = i % W2; int ek = i / W2;
  int nl = ek / KNN_K, k = ek % KNN_K;
  int n = n0 + nl;
  int j = idx[n*KNN_K + k];
  float out;
  if (c < CIN) out = xf[(size_t)j*227 + coff + c] - xf[(size_t)n*227 + coff + c];
  else         out = xf[(size_t)n*227 + coff + (c-CIN)];
  e[(size_t)ek*W2 + c] = out;
}

__global__ void kmax_k(const float* __restrict__ e2, int C, float* __restrict__ f1,
                       int n0, int np){
  int i = blockIdx.x*256 + threadIdx.x;
  if (i >= np*C) return;
  int nl = i / C, c = i % C;
  float v = -1e30f;
  for (int k=0;k<KNN_K;k++) v = fmaxf(v, e2[((size_t)nl*KNN_K+k)*C + c]);
  f1[(size_t)(n0+nl)*C + c] = v;
}

template<int C>
__global__ __launch_bounds__(256) void reduce1_k(const float* __restrict__ X, int n,
                                                 float* __restrict__ pmax, float* __restrict__ psum){
  const int tid = threadIdx.x;
  const int c = tid % C;
  const int r0 = tid / C;
  const int TPR = 256 / C;
  float vmax = -1e30f, vsum = 0.f;
  for (int row = blockIdx.x * TPR + r0; row < n; row += gridDim.x * TPR) {
    float v = X[(size_t)row * C + c];
    vmax = fmaxf(vmax, v); vsum += v;
  }
  __shared__ float smax[256], ssum[256];
  smax[tid]=vmax; ssum[tid]=vsum;
  __syncthreads();
  if (tid < C) {
    for (int q=1;q<TPR;q++){ vmax=fmaxf(vmax, smax[q*C+c]); vsum += ssum[q*C+c]; }
    pmax[blockIdx.x*C + c] = vmax; psum[blockIdx.x*C + c] = vsum;
  }
}

template<int C>
__global__ void reduce2_k(const float* __restrict__ pmax, const float* __restrict__ psum,
                          int nblk, float invn, float* __restrict__ fmaxo, float* __restrict__ favgo){
  int c = threadIdx.x; if (c >= C) return;
  float vmax=-1e30f, vsum=0.f;
  for (int b=0;b<nblk;b++){ vmax=fmaxf(vmax,pmax[b*C+c]); vsum+=psum[b*C+c]; }
  fmaxo[c]=vmax; favgo[c]=vsum*invn;
}

__global__ void concat_k(const float* __restrict__ xf, int coff, int CF,
                         const float* __restrict__ f1, int C,
                         const float* __restrict__ fmax, const float* __restrict__ favg,
                         float* __restrict__ h, int n0, int np){
  int W = CF + 3*C;
  int i = blockIdx.x*256 + threadIdx.x;
  if (i >= np*W) return;
  int nl = i / W, c = i % W;
  int n = n0 + nl;
  float v;
  if (c < CF)          v = xf[(size_t)n*227 + coff + c];
  else if (c < CF+C)   v = f1[(size_t)n*C + (c-CF)];
  else if (c < CF+2*C) v = fmax[c-CF-C];
  else                 v = favg[c-CF-2*C];
  h[(size_t)nl*W + c] = v;
}

__global__ void norms_k(const float* __restrict__ xf, float* __restrict__ nr){
  int n = blockIdx.x*256 + threadIdx.x;
  if (n >= N_PTS) return;
  const float* p = xf + (size_t)n*227 + 35;
  float s = 0.f;
  for (int d=0;d<64;d++) s += p[d]*p[d];
  nr[n] = s;
}

__global__ __launch_bounds__(64) void softgather_k(const float* __restrict__ logits,
                                                   const int* __restrict__ up_idx,
                                                   const float* __restrict__ xf,
                                                   float* __restrict__ z){
  __shared__ float lw[KUP]; __shared__ int li[KUP];
  int m = blockIdx.x;
  int tid = threadIdx.x;
  if (tid < KUP){ lw[tid] = logits[(size_t)m*KUP + tid]; li[tid] = up_idx[(size_t)m*KUP + tid]; }
  __syncthreads();
  float mx = -1e30f;
  for (int k=0;k<KUP;k++) mx = fmaxf(mx, lw[k]);
  __syncthreads();
  if (tid < KUP) lw[tid] = expf(lw[tid]-mx);
  __syncthreads();
  float s = 0.f;
  for (int k=0;k<KUP;k++) s += lw[k];
  float inv = 1.f/s;
  for (int c = tid; c < 227; c += 64){
    float acc = 0.f;
    for (int k=0;k<KUP;k++) acc += lw[k] * xf[(size_t)li[k]*227 + c];
    z[(size_t)m*227 + c] = acc*inv;
  }
}

// ---------------------------------------------------------------------------
extern "C" void kernel_launch(void* const* d_in, const int* in_sizes, int n_in,
                              void* d_out, int out_size, void* d_ws, size_t ws_size,
                              hipStream_t stream) {
  const int *idx0  = (const int*)d_in[3];
  const int *upidx = (const int*)d_in[37];

  // ---- workspace layout (floats) ----
  float* ws = (float*)d_ws;
  float* x_feat = ws;                     // [N,227]
  float* f1b    = ws + 3602944;           // [N,128]
  float* pmax   = ws + 5634560;
  float* psum   = ws + 5667328;
  float* fmaxv  = ws + 5700096;
  float* favgv  = ws + 5700224;
  int*   flag   = (int*)(ws + 5700352);
  int*   idx1   = (int*)(ws + 5700368);   // N*5
  float* nrm    = ws + 5779728;           // N
  float* logits = ws + 5795600;           // UP_ROWS
  float* wcvt   = ws + 6508352;           // 706,020 fp32 weights
  float* S      = ws + 7214400;           // scratch arena (9,662,464 floats)
  ushort_t* whi  = (ushort_t*)(S + 9662464);  // siren planes (114688 each)
  ushort_t* wlo  = whi + 114688;
  ushort_t* gwhi = wlo + 114688;              // mlp planes (196608 each)
  ushort_t* gwlo = gwhi + 196608;

  const size_t NEED = (size_t)(7214400 + 9662464) * 4
                    + (size_t)(114688*2 + 196608*2) * 2;   // ~68.8 MB
  if (ws_size < NEED) {
    fillmark_k<<<CDIV(out_size,256),256,0,stream>>>((bf16*)d_out, out_size);
    return;
  }

  // ---- dtype flag + one-shot weight conversion to fp32 ----
  flag_k<<<1,64,0,stream>>>((const uint*)d_in[2], flag);
  CvtTab tab;
  int wcoff = 0, seg = 0;
  auto CVT = [&](int i, int n)->const float* {
    tab.src[seg] = d_in[i]; tab.start[seg] = wcoff; seg++;
    const float* p = wcvt + wcoff; wcoff += n;
    return p;
  };
  const float *E0W1=CVT(4,8960),  *E0S1=CVT(5,128),  *E0H1=CVT(6,128),
              *E0W2=CVT(7,8192),  *E0B2=CVT(8,64);
  const float *F0W1=CVT(9,43584), *F0S1=CVT(10,192), *F0H1=CVT(11,192),
              *F0W2=CVT(12,24576),*F0S2=CVT(13,128), *F0H2=CVT(14,128),
              *F0W3=CVT(15,8192), *F0S3=CVT(16,64),  *F0H3=CVT(17,64),
              *F0W4=CVT(18,4096), *F0B4=CVT(19,64);
  const float *E1W1=CVT(20,32768),*E1S1=CVT(21,256), *E1H1=CVT(22,256),
              *E1W2=CVT(23,32768),*E1B2=CVT(24,128);
  const float *F1W1=CVT(25,172032),*F1S1=CVT(26,384),*F1H1=CVT(27,384),
              *F1W2=CVT(28,98304),*F1S2=CVT(29,256), *F1H2=CVT(30,256),
              *F1W3=CVT(31,32768),*F1S3=CVT(32,128), *F1H3=CVT(33,128),
              *F1W4=CVT(34,16384),*F1B4=CVT(35,128);
  const float *UPW0=CVT(38,896),  *UPS0=CVT(39,128), *UPH0=CVT(40,128),
              *UPWR=CVT(41,114688),*UPSR=CVT(42,896),*UPHR=CVT(43,896),
              *UPWF=CVT(44,128),  *UPBF=CVT(45,1);
  const float *DW0=CVT(46,58112), *DB0=CVT(47,256),
              *DW1=CVT(48,32768), *DB1=CVT(49,128),
              *DW2=CVT(50,8192),  *DB2=CVT(51,64),
              *DW3=CVT(52,2048),  *DB3=CVT(53,32),
              *DW4=CVT(54,512),   *DB4=CVT(55,16),
              *DWF=CVT(56,48),    *DBF=CVT(57,3);
  cvt_all_k<<<CDIV(wcoff,256),256,0,stream>>>(tab, wcvt, flag, wcoff);

  // siren planes
  packfrag_k<<<CDIV(114688,256),256,0,stream>>>(UPWR, whi, wlo, 114688);

  // mlp planes (fc0 + decoder, incl. head)
  int offs[10]; const float* srcs[10]; int Ns[10], Ks[10], Kps[10];
  {
    int o = 0, q = 0;
    auto REG = [&](const float* s, int N, int K, int Kpad){
      srcs[q]=s; Ns[q]=N; Ks[q]=K; Kps[q]=Kpad; offs[q]=o;
      o += CDIV(N,32)*32*Kpad; q++;
    };
    REG(F0W1,192,227,256); REG(F0W2,128,192,192); REG(F0W3,64,128,128); REG(F0W4,64,64,64);
    REG(DW0,256,227,256);  REG(DW1,128,256,256);  REG(DW2,64,128,128);
    REG(DW3,32,64,64);     REG(DW4,16,32,32);     REG(DWF,3,16,32);
  }
  for (int q = 0; q < 10; q++){
    int total = CDIV(Ns[q],32)*32*Kps[q];
    packw_mfma_k<<<CDIV(total,256),256,0,stream>>>(srcs[q], gwhi+offs[q], gwlo+offs[q],
                                                   Ns[q], Ks[q], Kps[q], total);
  }

  auto OFF = [&](const float* p){ return (int)(p - wcvt); };
  MCfg cfc0{};
  cfc0.L[0] = {227,192,8,6, offs[0], OFF(F0S1), OFF(F0H1), 0,1, 0.f};
  cfc0.L[1] = {192,128,6,4, offs[1], OFF(F0S2), OFF(F0H2), 0,1, 0.f};
  cfc0.L[2] = {128, 64,4,2, offs[2], OFF(F0S3), OFF(F0H3), 0,1, 0.f};
  cfc0.L[3] = { 64, 64,2,2, offs[3], 0,         OFF(F0B4), 1,0, 0.f};
  MCfg cdec{};
  cdec.L[0] = {227,256,8,8, offs[4], 0, OFF(DB0), 2,2, 30.f};
  cdec.L[1] = {256,128,8,4, offs[5], 0, OFF(DB1), 1,2, 0.f};
  cdec.L[2] = {128, 64,4,2, offs[6], 0, OFF(DB2), 1,2, 0.f};
  cdec.L[3] = { 64, 32,2,1, offs[7], 0, OFF(DB3), 1,2, 0.f};
  cdec.L[4] = { 32, 16,1,1, offs[8], 0, OFF(DB4), 1,2, 0.f};
  cdec.L[5] = { 16,  3,1,1, offs[9], 0, OFF(DBF), 1,0, 0.f};

  const float invN = 1.f/(float)N_PTS;
  const int CHP = 3072;    // edge-phase point chunk
  const int CHN = 8192;    // fc1-phase row chunk

  featin_k<<<CDIV(N_PTS*35,256),256,0,stream>>>(d_in[1], d_in[2], x_feat, flag);

  // ---- phase 1: emb block 0 (edge conv: fp32 gemm_k, round-7 proven)
  for (int n0 = 0; n0 < N_PTS; n0 += CHP) {
    int np = N_PTS - n0; if (np > CHP) np = CHP;
    int ne = np * KNN_K;
    float* eA = S;
    float* eB = S + 1075200;
    gather_e_k<<<CDIV(ne*70,256),256,0,stream>>>(x_feat, 0, 35, idx0, eA, n0, np);
    gemm_k<0,1><<<dim3(CDIV(ne,64),2),256,0,stream>>>(eA,70, E0W1,70, E0S1,E0H1,0.f, eB,128, ne,128,70);
    gemm_k<1,0><<<dim3(CDIV(ne,64),1),256,0,stream>>>(eB,128, E0W2,128, nullptr,E0B2,0.f, eA,64, ne,64,128);
    kmax_k<<<CDIV(np*64,256),256,0,stream>>>(eA, 64, f1b, n0, np);
  }
  reduce1_k<64><<<256,256,0,stream>>>(f1b, N_PTS, pmax, psum);
  reduce2_k<64><<<1,64,0,stream>>>(pmax, psum, 256, invN, fmaxv, favgv);
  // fc0: full concat then ONE fused MLP
  {
    float* h = S;   // [N,227]
    concat_k<<<CDIV(N_PTS*227,256),256,0,stream>>>(x_feat,0,35, f1b,64, fmaxv,favgv, h, 0, N_PTS);
    mlp_fused_k<4,0><<<CDIV(N_PTS,64),256,0,stream>>>(
        h,227,227,N_PTS, cfc0, gwhi,gwlo,wcvt, x_feat+35,227, nullptr, flag);
  }

  // ---- phase 2: dynamic KNN (MFMA)
  norms_k<<<CDIV(N_PTS,256),256,0,stream>>>(x_feat, nrm);
  {
    const int PLANE = NTILE*5*64*8;
    ushort_t* ajhi = (ushort_t*)S;
    ushort_t* ajlo = ajhi + PLANE;
    ushort_t* bihi = ajlo + PLANE;
    ushort_t* bilo = bihi + PLANE;
    packknn_k<<<CDIV(PLANE,256),256,0,stream>>>(x_feat, nrm, ajhi, ajlo, bihi, bilo);
    knn_mfma_k<<<NTILE,256,0,stream>>>(ajhi, ajlo, bihi, bilo, idx1);
  }

  // ---- phase 3: emb block 1 (edge conv fp32 gemm_k; fc1 fp32 gemm_k)
  for (int n0 = 0; n0 < N_PTS; n0 += CHP) {
    int np = N_PTS - n0; if (np > CHP) np = CHP;
    int ne = np * KNN_K;
    float* eA = S;
    float* eB = S + 1966080;
    gather_e_k<<<CDIV(ne*128,256),256,0,stream>>>(x_feat, 35, 64, idx1, eA, n0, np);
    gemm_k<0,1><<<dim3(CDIV(ne,64),4),256,0,stream>>>(eA,128, E1W1,128, E1S1,E1H1,0.f, eB,256, ne,256,128);
    gemm_k<1,0><<<dim3(CDIV(ne,64),2),256,0,stream>>>(eB,256, E1W2,256, nullptr,E1B2,0.f, eA,128, ne,128,256);
    kmax_k<<<CDIV(np*128,256),256,0,stream>>>(eA, 128, f1b, n0, np);
  }
  reduce1_k<128><<<256,256,0,stream>>>(f1b, N_PTS, pmax, psum);
  reduce2_k<128><<<1,128,0,stream>>>(pmax, psum, 256, invN, fmaxv, favgv);
  for (int n0 = 0; n0 < N_PTS; n0 += CHN) {
    int np = N_PTS - n0; if (np > CHN) np = CHN;
    float* h  = S;
    float* a1 = S + 3670016;
    int gx = CDIV(np,64);
    concat_k<<<CDIV(np*448,256),256,0,stream>>>(x_feat,35,64, f1b,128, fmaxv,favgv, h, n0, np);
    gemm_k<0,1><<<dim3(gx,6),256,0,stream>>>(h,448,  F1W1,448, F1S1,F1H1,0.f, a1,384, np,384,448);
    gemm_k<0,1><<<dim3(gx,4),256,0,stream>>>(a1,384, F1W2,384, F1S2,F1H2,0.f, h,256,  np,256,384);
    gemm_k<0,1><<<dim3(gx,2),256,0,stream>>>(h,256,  F1W3,256, F1S3,F1H3,0.f, a1,128, np,128,256);
    gemm_k<1,0><<<dim3(gx,2),256,0,stream>>>(a1,128, F1W4,128, nullptr,F1B4,0.f, x_feat+(size_t)n0*227+99,227, np,128,128);
  }

  // ---- phase 4: fused SIREN -> logits; softmax gather -> z
  siren_fused_k<<<CDIV(UP_ROWS,128),256,0,stream>>>(
      d_in[36], whi, wlo, UPW0, UPS0, UPH0, UPSR, UPHR, UPWF, UPBF, logits, flag);
  float* zbuf = S;                 // [M,227]
  softgather_k<<<M_PTS,64,0,stream>>>(logits, upidx, x_feat, zbuf);

  // ---- phase 5: SIREN decoder: ONE fused MLP (incl. 16->3 head + output)
  mlp_fused_k<6,1><<<CDIV(M_PTS,64),256,0,stream>>>(
      zbuf,227,227,M_PTS, cdec, gwhi,gwlo,wcvt, nullptr,0, d_out, flag);
}

// Round 12
// 2297.197 us; speedup vs baseline: 1.5464x; 1.0027x over previous
//
#include <hip/hip_runtime.h>
#include <hip/hip_bf16.h>
#include <math.h>

#define N_PTS 15872
#define M_PTS 35637
#define KNN_K 5
#define KUP   20
#define UP_ROWS (M_PTS * KUP)   // 712740
#define NTILE (N_PTS/32)        // 496 i/j tiles
#define N_EDGE (N_PTS*KNN_K)    // 79360
#define CDIV(a,b) (((a)+(b)-1)/(b))

typedef __hip_bfloat16 bf16;
typedef unsigned int uint;
typedef unsigned short ushort_t;
__device__ __forceinline__ float b2f(bf16 x){ return __bfloat162float(x); }

// round-to-nearest-even fp32 -> bf16 bit pattern (finite inputs)
__device__ __forceinline__ uint f2bf_bits(float x){
  uint u = __float_as_uint(x);
  return (u + 0x7FFFu + ((u>>16)&1u)) >> 16;
}

typedef __attribute__((ext_vector_type(8))) short bf16x8;
typedef __attribute__((ext_vector_type(16))) float f32x16;
union FragAB { bf16x8 v; uint u[4]; };
union FragB  { bf16x8 v; uint4 q; };
union Acc16  { f32x16 v; float f[16]; };

// ---------------------------------------------------------------------------
__global__ void flag_k(const uint* __restrict__ pos_raw, int* __restrict__ flag){
  if (threadIdx.x == 0 && blockIdx.x == 0)
    flag[0] = (pos_raw[0] == 0x3F800000u) ? 1 : 0;
}

struct CvtTab { const void* src[52]; int start[52]; };
__global__ __launch_bounds__(256) void cvt_all_k(CvtTab tab, float* __restrict__ dst,
                                                 const int* __restrict__ flag, int total){
  int i = blockIdx.x*256 + threadIdx.x;
  if (i >= total) return;
  int s = 0;
#pragma unroll 1
  for (int k = 1; k < 52; k++) if (tab.start[k] <= i) s = k;
  int off = i - tab.start[s];
  float v = flag[0] ? b2f(((const bf16*)tab.src[s])[off]) : ((const float*)tab.src[s])[off];
  dst[i] = v;
}

// pack SIREN 128x128 weights into frag-major split-bf16 hi/lo planes.
__global__ void packfrag_k(const float* __restrict__ w, ushort_t* __restrict__ whi,
                           ushort_t* __restrict__ wlo, int n){
  int i = blockIdx.x*256 + threadIdx.x;
  if (i >= n) return;
  int j = i & 7;
  int lam = (i >> 3) & 63;
  int fg = i >> 9;
  int t = fg & 3, ks = (fg >> 2) & 1, Q = (fg >> 3) & 3, l = fg >> 5;
  int nn = t*32 + (lam & 31);
  int kk = Q*32 + ks*16 + (lam >> 5)*8 + j;
  float x = w[l*16384 + nn*128 + kk];
  uint hb = f2bf_bits(x);
  uint lb = f2bf_bits(x - __uint_as_float(hb << 16));
  whi[i] = (ushort_t)hb;
  wlo[i] = (ushort_t)lb;
}

// generic frag-major split-bf16 pack for weight matrix W[N][K] (row-major),
// K padded to Kpad (x32), N padded to x32 with zeros.
__global__ void packw_mfma_k(const float* __restrict__ w, ushort_t* __restrict__ whi,
                             ushort_t* __restrict__ wlo, int N, int K, int Kpad, int total){
  int i = blockIdx.x*256 + threadIdx.x;
  if (i >= total) return;
  int j = i & 7;
  int lane = (i >> 3) & 63;
  int fr = i >> 9;
  int nq = Kpad >> 5;
  int ks = fr & 1;
  int q  = (fr >> 1) % nq;
  int nt = (fr >> 1) / nq;
  int n = nt*32 + (lane & 31);
  int k = q*32 + ks*16 + (lane >> 5)*8 + j;
  float x = (n < N && k < K) ? w[(size_t)n*K + k] : 0.f;
  uint hb = f2bf_bits(x);
  uint lb = f2bf_bits(x - __uint_as_float(hb << 16));
  whi[i] = (ushort_t)hb;
  wlo[i] = (ushort_t)lb;
}

// pack KNN features into frag-major split-bf16 planes with norm augmentation.
__global__ void packknn_k(const float* __restrict__ xf, const float* __restrict__ nr,
                          ushort_t* __restrict__ ahi, ushort_t* __restrict__ alo,
                          ushort_t* __restrict__ bhi, ushort_t* __restrict__ blo){
  int i = blockIdx.x*256 + threadIdx.x;
  if (i >= NTILE*5*64*8) return;
  int e = i & 7;
  int lane = (i >> 3) & 63;
  int rest = i >> 9;
  int kc = rest % 5, jt = rest / 5;
  int n = jt*32 + (lane & 31);
  int k = kc*16 + (lane >> 5)*8 + e;
  float f = (k < 64) ? xf[(size_t)n*227 + 35 + k] : 0.f;
  float av, bv;
  if (k < 64)      { av = 2.f*f;   bv = f; }
  else if (k == 64){ av = nr[n];   bv = -1.f; }
  else if (k == 65){ av = 1.f;     bv = -nr[n]; }
  else             { av = 0.f;     bv = 0.f; }
  uint ah = f2bf_bits(av); uint al = f2bf_bits(av - __uint_as_float(ah<<16));
  uint bh = f2bf_bits(bv); uint bl = f2bf_bits(bv - __uint_as_float(bh<<16));
  ahi[i] = (ushort_t)ah; alo[i] = (ushort_t)al;
  bhi[i] = (ushort_t)bh; blo[i] = (ushort_t)bl;
}

__global__ void fillmark_k(bf16* __restrict__ out, int n){
  int i = blockIdx.x*256 + threadIdx.x;
  if (i < n) out[i] = __float2bfloat16(12345.0f);
}

// ---------------------------------------------------------------------------
// fp32 fused GEMM (round-7 proven; used for fc1 first two layers)
// ---------------------------------------------------------------------------
template<int EPI, int ACT>
__global__ __launch_bounds__(256) void gemm_k(
    const float* __restrict__ A, int lda,
    const float* __restrict__ W, int ldw,
    const float* __restrict__ scale, const float* __restrict__ shift,
    float gmul, float* __restrict__ C, int ldc,
    int M, int Nout, int K)
{
  __shared__ __align__(16) float As[16][64];
  __shared__ __align__(16) float Ws[16][64];
  const int tid = threadIdx.x;
  const int tx = tid & 15, ty = tid >> 4;
  const int bm = blockIdx.x * 64, bn = blockIdx.y * 64;
  const int ar = tid >> 2, ak = (tid & 3) * 4;
  float acc[4][4] = {};
  for (int k0 = 0; k0 < K; k0 += 16) {
    float a0=0.f,a1=0.f,a2=0.f,a3=0.f;
    int grow = bm + ar;
    if (grow < M) {
      const float* ap = A + (size_t)grow * lda + (k0 + ak);
      int rem = K - (k0 + ak);
      if (rem >= 4) { a0=ap[0]; a1=ap[1]; a2=ap[2]; a3=ap[3]; }
      else { if(rem>0)a0=ap[0]; if(rem>1)a1=ap[1]; if(rem>2)a2=ap[2]; }
    }
    float w0=0.f,w1=0.f,w2=0.f,w3=0.f;
    int gn = bn + ar;
    if (gn < Nout) {
      const float* wp = W + (size_t)gn * ldw + (k0 + ak);
      int rem = K - (k0 + ak);
      if (rem >= 4) { w0=wp[0]; w1=wp[1]; w2=wp[2]; w3=wp[3]; }
      else { if(rem>0)w0=wp[0]; if(rem>1)w1=wp[1]; if(rem>2)w2=wp[2]; }
    }
    __syncthreads();
    As[ak+0][ar]=a0; As[ak+1][ar]=a1; As[ak+2][ar]=a2; As[ak+3][ar]=a3;
    Ws[ak+0][ar]=w0; Ws[ak+1][ar]=w1; Ws[ak+2][ar]=w2; Ws[ak+3][ar]=w3;
    __syncthreads();
#pragma unroll
    for (int kk = 0; kk < 16; kk++) {
      float4 av = *reinterpret_cast<const float4*>(&As[kk][ty*4]);
      float4 wv = *reinterpret_cast<const float4*>(&Ws[kk][tx*4]);
      float aa[4] = {av.x,av.y,av.z,av.w};
      float ww[4] = {wv.x,wv.y,wv.z,wv.w};
#pragma unroll
      for (int i=0;i<4;i++)
#pragma unroll
        for (int j=0;j<4;j++) acc[i][j] += aa[i]*ww[j];
    }
  }
#pragma unroll
  for (int i=0;i<4;i++){
    int m = bm + ty*4 + i;
    if (m >= M) continue;
#pragma unroll
    for (int j=0;j<4;j++){
      int n = bn + tx*4 + j;
      if (n >= Nout) continue;
      float v = acc[i][j];
      if (EPI==0)      v = v * scale[n] + shift[n];
      else if (EPI==1) v = v + shift[n];
      else             v = (v + shift[n]) * gmul;
      if (ACT==1)      v = v > 0.f ? v : 0.2f*v;
      else if (ACT==2) v = sinf(v);
      C[(size_t)m*ldc + n] = v;
    }
  }
}

// ---------------------------------------------------------------------------
// Generic fused per-row MLP (validated round 9): up to 6 layers, dims <= 256.
// Block 256 = 4 waves: wave = (row-half, tile-half). 64 rows/block.
// Activations packed split-bf16 u32 in swizzled LDS slab [64][256].
// OUTMODE 0: final layer -> fp32 Cout[row*ldc+col].
// OUTMODE 1: final layer -> flagged bf16/fp32 at oflg[row*3+col] (canary).
// ---------------------------------------------------------------------------
struct MLayer { int K, N, Kq, Nt, woff, soff, hoff, epi, act; float gmul; };
struct MCfg { MLayer L[6]; };

template<int NL, int OUTMODE>
__global__ __launch_bounds__(256) void mlp_fused_k(
    const float* __restrict__ A0, int lda0, int K0, int M,
    MCfg cfg,
    const ushort_t* __restrict__ wh, const ushort_t* __restrict__ wl,
    const float* __restrict__ wc,
    float* __restrict__ Cout, int ldc,
    void* __restrict__ oflg, const int* __restrict__ flag)
{
  __shared__ __align__(16) uint slab[64*256];   // 65536 B
  const int tid = threadIdx.x;
  const int lane = tid & 63;
  const int wv = tid >> 6;
  const int np = lane & 31;
  const int hb2 = lane >> 5;
  const int rhalf = wv & 1, thalf = wv >> 1;
  const int rb = blockIdx.x * 64;
  const int row_l = rhalf*32 + np;

  for (int e = tid; e < 64*64; e += 256) {
    int r = e >> 6, g = e & 63;
    int gr = rb + r;
    uint p[4];
#pragma unroll
    for (int u=0;u<4;u++){
      int k = g*4+u;
      float f = (gr < M && k < K0) ? A0[(size_t)gr*lda0 + k] : 0.f;
      uint hb = f2bf_bits(f);
      uint lb = f2bf_bits(f - __uint_as_float(hb<<16));
      p[u] = (hb<<16) | lb;
    }
    *(uint4*)&slab[r*256 + (((g ^ r) & 63)<<2)] = make_uint4(p[0],p[1],p[2],p[3]);
  }
  __syncthreads();

#pragma unroll 1
  for (int l = 0; l < NL; l++){
    const int N = cfg.L[l].N, Kq = cfg.L[l].Kq, Nt = cfg.L[l].Nt;
    const int woff = cfg.L[l].woff, soff = cfg.L[l].soff, hoff = cfg.L[l].hoff;
    const int epi = cfg.L[l].epi, actf = cfg.L[l].act;
    const float gmul = cfg.L[l].gmul;
    Acc16 acc[4];
#pragma unroll
    for (int u=0;u<4;u++)
#pragma unroll
      for (int i=0;i<16;i++) acc[u].f[i] = 0.f;

#pragma unroll 1
    for (int q = 0; q < Kq; q++){
#pragma unroll
      for (int ks = 0; ks < 2; ks++){
        int g0 = (q*32 + ks*16 + hb2*8) >> 2;
        uint4 a0 = *(const uint4*)&slab[row_l*256 + ((((g0  ) ^ row_l) & 63)<<2)];
        uint4 a1 = *(const uint4*)&slab[row_l*256 + ((((g0+1) ^ row_l) & 63)<<2)];
        uint au[8] = {a0.x,a0.y,a0.z,a0.w,a1.x,a1.y,a1.z,a1.w};
        FragAB ah, al;
#pragma unroll
        for (int p=0;p<4;p++){
          ah.u[p] = (au[2*p]>>16)     | (au[2*p+1] & 0xFFFF0000u);
          al.u[p] = (au[2*p]&0xFFFFu) | (au[2*p+1]<<16);
        }
#pragma unroll
        for (int u=0;u<4;u++){
          int t = thalf + u*2;
          if (t < Nt){
            size_t fb = (size_t)woff + ((size_t)((t*Kq + q)*2 + ks))*512 + (size_t)lane*8;
            FragB bh, bl;
            bh.q = *(const uint4*)(wh + fb);
            bl.q = *(const uint4*)(wl + fb);
            acc[u].v = __builtin_amdgcn_mfma_f32_32x32x16_bf16(ah.v, bh.v, acc[u].v, 0,0,0);
            acc[u].v = __builtin_amdgcn_mfma_f32_32x32x16_bf16(al.v, bh.v, acc[u].v, 0,0,0);
            acc[u].v = __builtin_amdgcn_mfma_f32_32x32x16_bf16(ah.v, bl.v, acc[u].v, 0,0,0);
          }
        }
      }
    }
    __syncthreads();
#pragma unroll
    for (int u=0;u<4;u++){
      int t = thalf + u*2;
      if (t < Nt){
        int col = t*32 + np;
        if (col < N){
          float scv = (epi==0) ? wc[soff+col] : 0.f;
          float shv = wc[hoff+col];
#pragma unroll
          for (int reg=0;reg<16;reg++){
            int r32 = (reg&3) + 8*(reg>>2) + 4*hb2;
            float v = acc[u].f[reg];
            if (epi==0)      v = v*scv + shv;
            else if (epi==1) v = v + shv;
            else             v = (v + shv)*gmul;
            if (actf==1)      v = v > 0.f ? v : 0.2f*v;
            else if (actf==2) v = __sinf(v);
            if (l == NL-1){
              int gr = rb + rhalf*32 + r32;
              if (gr < M){
                if (OUTMODE==0) Cout[(size_t)gr*ldc + col] = v;
                else {
                  if (!(fabsf(v) < 1e30f)) v = 777.0f;  // canary
                  size_t oi = (size_t)gr*3 + col;
                  if (flag[0]) ((bf16*)oflg)[oi] = __float2bfloat16(v);
                  else         ((float*)oflg)[oi] = v;
                }
              }
            } else {
              int r = rhalf*32 + r32;
              uint hb = f2bf_bits(v);
              uint lb = f2bf_bits(v - __uint_as_float(hb<<16));
              slab[r*256 + ((((col>>2) ^ r) & 63)<<2) + (col&3)] = (hb<<16) | lb;
            }
          }
        }
      }
    }
    __syncthreads();
  }
}

// ---------------------------------------------------------------------------
// MFMA KNN (validated round 7).
// ---------------------------------------------------------------------------
#define INS5(tv, tj, v, j) \
  if ((v) > tv[4]){ tv[4]=(v); tj[4]=(j); \
    _Pragma("unroll") \
    for (int q=4;q>0;q--) \
      if (tv[q] > tv[q-1]){ float tf=tv[q-1]; tv[q-1]=tv[q]; tv[q]=tf; \
                            int ti=tj[q-1]; tj[q-1]=tj[q]; tj[q]=ti; } }

__global__ __launch_bounds__(256) void knn_mfma_k(
    const ushort_t* __restrict__ ahi, const ushort_t* __restrict__ alo,
    const ushort_t* __restrict__ bhi, const ushort_t* __restrict__ blo,
    int* __restrict__ out)
{
  __shared__ float mv[4][32][5];
  __shared__ int   mjj[4][32][5];
  const int tid = threadIdx.x;
  const int lane = tid & 63;
  const int wv = tid >> 6;
  const int np = lane & 31;
  const int hb2 = lane >> 5;
  const int it = blockIdx.x;
  const int ig = it*32 + np;

  FragB vh[5], vl[5];
  {
    size_t bb = (size_t)(it*5)*512 + (size_t)lane*8;
#pragma unroll
    for (int kc=0;kc<5;kc++){
      vh[kc].q = *(const uint4*)(bhi + bb + kc*512);
      vl[kc].q = *(const uint4*)(blo + bb + kc*512);
    }
  }

  float tv[5] = {-1e30f,-1e30f,-1e30f,-1e30f,-1e30f};
  int   tj[5] = {0,0,0,0,0};

  FragB uh[5], ul[5], nh[5], nl[5];
  {
    size_t ab = (size_t)(wv*5)*512 + (size_t)lane*8;
#pragma unroll
    for (int kc=0;kc<5;kc++){
      uh[kc].q = *(const uint4*)(ahi + ab + kc*512);
      ul[kc].q = *(const uint4*)(alo + ab + kc*512);
    }
  }

#pragma unroll 1
  for (int t = 0; t < NTILE/4; t++){
    int jt = wv + t*4;
    if (t+1 < NTILE/4){
      size_t an = (size_t)((jt+4)*5)*512 + (size_t)lane*8;
#pragma unroll
      for (int kc=0;kc<5;kc++){
        nh[kc].q = *(const uint4*)(ahi + an + kc*512);
        nl[kc].q = *(const uint4*)(alo + an + kc*512);
      }
    }
    Acc16 acc;
#pragma unroll
    for (int q=0;q<16;q++) acc.f[q] = 0.f;
#pragma unroll
    for (int kc=0;kc<5;kc++){
      acc.v = __builtin_amdgcn_mfma_f32_32x32x16_bf16(uh[kc].v, vh[kc].v, acc.v, 0,0,0);
      acc.v = __builtin_amdgcn_mfma_f32_32x32x16_bf16(ul[kc].v, vh[kc].v, acc.v, 0,0,0);
      acc.v = __builtin_amdgcn_mfma_f32_32x32x16_bf16(uh[kc].v, vl[kc].v, acc.v, 0,0,0);
    }
    int jb = jt*32 + 4*hb2;
#pragma unroll
    for (int reg=0;reg<16;reg++){
      int j = jb + (reg&3) + 8*(reg>>2);
      float v = acc.f[reg];
      if (j != ig) { INS5(tv, tj, v, j); }
    }
    if (t+1 < NTILE/4){
#pragma unroll
      for (int kc=0;kc<5;kc++){ uh[kc] = nh[kc]; ul[kc] = nl[kc]; }
    }
  }

#pragma unroll
  for (int s=0;s<5;s++){
    float ov = __shfl_xor(tv[s], 32, 64);
    int   oj = __shfl_xor(tj[s], 32, 64);
    INS5(tv, tj, ov, oj);
  }
  if (hb2 == 0){
#pragma unroll
    for (int s=0;s<5;s++){ mv[wv][np][s] = tv[s]; mjj[wv][np][s] = tj[s]; }
  }
  __syncthreads();
  if (tid < 32){
    float bv[5]; int bj[5];
#pragma unroll
    for (int s=0;s<5;s++){ bv[s] = mv[0][tid][s]; bj[s] = mjj[0][tid][s]; }
#pragma unroll
    for (int w=1;w<4;w++)
#pragma unroll
      for (int s=0;s<5;s++){
        float v = mv[w][tid][s]; int j = mjj[w][tid][s];
        INS5(bv, bj, v, j);
      }
    int gi = it*32 + tid;
#pragma unroll
    for (int s=0;s<5;s++) out[gi*KNN_K + s] = bj[s];
  }
}

// ---------------------------------------------------------------------------
// Fused 8-layer SIREN + head. v3 (validated round 11): wave-private act slab,
// no per-layer barriers, truncation-split hi.
// ---------------------------------------------------------------------------
__global__ __launch_bounds__(256, 2) void siren_fused_k(
    const void* __restrict__ upin,
    const ushort_t* __restrict__ whi, const ushort_t* __restrict__ wlo,
    const float* __restrict__ W0c, const float* __restrict__ S0c, const float* __restrict__ H0c,
    const float* __restrict__ SRc, const float* __restrict__ HRc,
    const float* __restrict__ WFc, const float* __restrict__ BFc,
    float* __restrict__ logits, const int* __restrict__ flag)
{
  __shared__ __align__(16) uint act[4*32*128];
  __shared__ float intile[4*32*8];
  __shared__ float w0s[128*9];
  __shared__ float wfs[128];
  __shared__ float bfs[1];

  const int tid  = threadIdx.x;
  const int lane = tid & 63;
  const int wv   = tid >> 6;
  const int np   = lane & 31;
  const int hb2  = lane >> 5;
  const int rowbase = blockIdx.x * 128 + wv * 32;
  const int isbf = flag[0];
  uint*  actw = act + wv*32*128;
  float* intw = intile + wv*32*8;

  for (int e = tid; e < 128*7; e += 256) w0s[(e/7)*9 + (e%7)] = W0c[e];
  if (tid < 128) wfs[tid] = WFc[tid];
  if (tid == 0) bfs[0] = BFc[0];
  for (int e = lane; e < 32*7; e += 64) {
    int r = e/7, k = e%7;
    int gr = rowbase + r;
    float v = 0.f;
    if (gr < UP_ROWS)
      v = isbf ? b2f(((const bf16*)upin)[(size_t)gr*7+k]) : ((const float*)upin)[(size_t)gr*7+k];
    intw[r*8+k] = v;
  }
  __syncthreads();   // block-shared staging (w0s/wfs/bfs) -- must stay

#pragma unroll
  for (int t = 0; t < 4; t++) {
    int c = t*32 + np;
    float s = S0c[c], b = H0c[c];
#pragma unroll
    for (int reg = 0; reg < 16; reg++) {
      int r = (reg&3) + 8*(reg>>2) + 4*hb2;
      float a = 0.f;
#pragma unroll
      for (int k = 0; k < 7; k++) a += intw[r*8+k]*w0s[c*9+k];
      float x = __sinf(a*s + b);
      uint xu = __float_as_uint(x);
      uint hbi = xu >> 16;                               // trunc hi
      uint lbi = f2bf_bits(x - __uint_as_float(hbi<<16)); // RNE residual
      int col = (c & 3) | ((((c>>2) ^ r) & 31) << 2);
      actw[r*128 + col] = (hbi<<16) | lbi;
    }
  }

  // layers 1..7: act slab is wave-private -> no __syncthreads needed
#pragma unroll 1
  for (int l = 0; l < 7; l++) {
    float sc[4], sh[4];
#pragma unroll
    for (int t=0;t<4;t++){ sc[t] = SRc[l*128 + t*32 + np]; sh[t] = HRc[l*128 + t*32 + np]; }
    Acc16 acc[4];
#pragma unroll
    for (int t=0;t<4;t++)
#pragma unroll
      for (int i=0;i<16;i++) acc[t].f[i] = 0.f;

#pragma unroll 1
    for (int Q = 0; Q < 4; Q++) {
#pragma unroll
      for (int ks = 0; ks < 2; ks++) {
        int g0 = (Q*32 + ks*16 + hb2*8) >> 2;
        uint4 a0 = *(const uint4*)&actw[np*128 + ((g0 ^ np) << 2)];
        uint4 a1 = *(const uint4*)&actw[np*128 + (((g0+1) ^ np) << 2)];
        uint au[8] = {a0.x,a0.y,a0.z,a0.w,a1.x,a1.y,a1.z,a1.w};
        FragAB ahi, alo;
#pragma unroll
        for (int p=0;p<4;p++){
          ahi.u[p] = (au[2*p]>>16)     | (au[2*p+1] & 0xFFFF0000u);
          alo.u[p] = (au[2*p]&0xFFFFu) | (au[2*p+1]<<16);
        }
        size_t fb = ((size_t)(((l*4 + Q)*2 + ks)*4) << 9) + (size_t)lane*8;
        FragB bh[4], bl[4];
#pragma unroll
        for (int t=0;t<4;t++){
          bh[t].q = *(const uint4*)(whi + fb + (size_t)t*512);
          bl[t].q = *(const uint4*)(wlo + fb + (size_t)t*512);
        }
#pragma unroll
        for (int t=0;t<4;t++){
          acc[t].v = __builtin_amdgcn_mfma_f32_32x32x16_bf16(ahi.v, bh[t].v, acc[t].v, 0,0,0);
          acc[t].v = __builtin_amdgcn_mfma_f32_32x32x16_bf16(alo.v, bh[t].v, acc[t].v, 0,0,0);
          acc[t].v = __builtin_amdgcn_mfma_f32_32x32x16_bf16(ahi.v, bl[t].v, acc[t].v, 0,0,0);
        }
      }
    }
#pragma unroll
    for (int t=0;t<4;t++){
      int c = t*32 + np;
#pragma unroll
      for (int reg=0;reg<16;reg++){
        int r = (reg&3) + 8*(reg>>2) + 4*hb2;
        float x = __sinf(acc[t].f[reg]*sc[t] + sh[t]);
        uint xu = __float_as_uint(x);
        uint hbi = xu >> 16;
        uint lbi = f2bf_bits(x - __uint_as_float(hbi<<16));
        int col = (c & 3) | ((((c>>2) ^ r) & 31) << 2);
        actw[r*128 + col] = (hbi<<16) | lbi;
      }
    }
  }

  {
    float a = 0.f;
#pragma unroll
    for (int g = 0; g < 16; g++) {
      int gg = hb2*16 + g;
      uint4 u = *(const uint4*)&actw[np*128 + ((gg ^ np) << 2)];
      int kb = gg*4;
      float x0 = __uint_as_float(u.x & 0xFFFF0000u) + __uint_as_float(u.x<<16);
      float x1 = __uint_as_float(u.y & 0xFFFF0000u) + __uint_as_float(u.y<<16);
      float x2 = __uint_as_float(u.z & 0xFFFF0000u) + __uint_as_float(u.z<<16);
      float x3 = __uint_as_float(u.w & 0xFFFF0000u) + __uint_as_float(u.w<<16);
      a += x0*wfs[kb] + x1*wfs[kb+1] + x2*wfs[kb+2] + x3*wfs[kb+3];
    }
    a += __shfl_xor(a, 32, 64);
    int gr = rowbase + np;
    if (hb2 == 0 && gr < UP_ROWS) logits[gr] = a + bfs[0];
  }
}

// ---------------------------------------------------------------------------
__global__ void featin_k(const void* __restrict__ ldx, const void* __restrict__ pos,
                         float* __restrict__ xf, const int* __restrict__ flag){
  int i = blockIdx.x*256 + threadIdx.x;
  if (i >= N_PTS*35) return;
  int n = i / 35, c = i % 35;
  float v;
  if (flag[0]) {
    v = (c < 3) ? b2f(((const bf16*)ldx)[n*3+c]) : b2f(((const bf16*)pos)[n*32 + (c-3)]);
  } else {
    v = (c < 3) ? ((const float*)ldx)[n*3+c] : ((const float*)pos)[n*32 + (c-3)];
  }
  xf[(size_t)n*227 + c] = v;
}

__global__ void gather_e_k(const float* __restrict__ xf, int coff, int CIN,
                           const int* __restrict__ idx, float* __restrict__ e,
                           int n0, int np){
  int W2 = 2*CIN;
  int i = blockIdx.x*256 + threadIdx.x;
  if (i >= np*KNN_K*W2) return;
  int c = i % W2; int ek = i / W2;
  int nl = ek / KNN_K, k = ek % KNN_K;
  int n = n0 + nl;
  int j = idx[n*KNN_K + k];
  float out;
  if (c < CIN) out = xf[(size_t)j*227 + coff + c] - xf[(size_t)n*227 + coff + c];
  else         out = xf[(size_t)n*227 + coff + (c-CIN)];
  e[(size_t)ek*W2 + c] = out;
}

__global__ void kmax_k(const float* __restrict__ e2, int C, float* __restrict__ f1,
                       int n0, int np){
  int i = blockIdx.x*256 + threadIdx.x;
  if (i >= np*C) return;
  int nl = i / C, c = i % C;
  float v = -1e30f;
  for (int k=0;k<KNN_K;k++) v = fmaxf(v, e2[((size_t)nl*KNN_K+k)*C + c]);
  f1[(size_t)(n0+nl)*C + c] = v;
}

template<int C>
__global__ __launch_bounds__(256) void reduce1_k(const float* __restrict__ X, int n,
                                                 float* __restrict__ pmax, float* __restrict__ psum){
  const int tid = threadIdx.x;
  const int c = tid % C;
  const int r0 = tid / C;
  const int TPR = 256 / C;
  float vmax = -1e30f, vsum = 0.f;
  for (int row = blockIdx.x * TPR + r0; row < n; row += gridDim.x * TPR) {
    float v = X[(size_t)row * C + c];
    vmax = fmaxf(vmax, v); vsum += v;
  }
  __shared__ float smax[256], ssum[256];
  smax[tid]=vmax; ssum[tid]=vsum;
  __syncthreads();
  if (tid < C) {
    for (int q=1;q<TPR;q++){ vmax=fmaxf(vmax, smax[q*C+c]); vsum += ssum[q*C+c]; }
    pmax[blockIdx.x*C + c] = vmax; psum[blockIdx.x*C + c] = vsum;
  }
}

template<int C>
__global__ void reduce2_k(const float* __restrict__ pmax, const float* __restrict__ psum,
                          int nblk, float invn, float* __restrict__ fmaxo, float* __restrict__ favgo){
  int c = threadIdx.x; if (c >= C) return;
  float vmax=-1e30f, vsum=0.f;
  for (int b=0;b<nblk;b++){ vmax=fmaxf(vmax,pmax[b*C+c]); vsum+=psum[b*C+c]; }
  fmaxo[c]=vmax; favgo[c]=vsum*invn;
}

__global__ void concat_k(const float* __restrict__ xf, int coff, int CF,
                         const float* __restrict__ f1, int C,
                         const float* __restrict__ fmax, const float* __restrict__ favg,
                         float* __restrict__ h, int n0, int np){
  int W = CF + 3*C;
  int i = blockIdx.x*256 + threadIdx.x;
  if (i >= np*W) return;
  int nl = i / W, c = i % W;
  int n = n0 + nl;
  float v;
  if (c < CF)          v = xf[(size_t)n*227 + coff + c];
  else if (c < CF+C)   v = f1[(size_t)n*C + (c-CF)];
  else if (c < CF+2*C) v = fmax[c-CF-C];
  else                 v = favg[c-CF-2*C];
  h[(size_t)nl*W + c] = v;
}

__global__ void norms_k(const float* __restrict__ xf, float* __restrict__ nr){
  int n = blockIdx.x*256 + threadIdx.x;
  if (n >= N_PTS) return;
  const float* p = xf + (size_t)n*227 + 35;
  float s = 0.f;
  for (int d=0;d<64;d++) s += p[d]*p[d];
  nr[n] = s;
}

__global__ __launch_bounds__(64) void softgather_k(const float* __restrict__ logits,
                                                   const int* __restrict__ up_idx,
                                                   const float* __restrict__ xf,
                                                   float* __restrict__ z){
  __shared__ float lw[KUP]; __shared__ int li[KUP];
  int m = blockIdx.x;
  int tid = threadIdx.x;
  if (tid < KUP){ lw[tid] = logits[(size_t)m*KUP + tid]; li[tid] = up_idx[(size_t)m*KUP + tid]; }
  __syncthreads();
  float mx = -1e30f;
  for (int k=0;k<KUP;k++) mx = fmaxf(mx, lw[k]);
  __syncthreads();
  if (tid < KUP) lw[tid] = expf(lw[tid]-mx);
  __syncthreads();
  float s = 0.f;
  for (int k=0;k<KUP;k++) s += lw[k];
  float inv = 1.f/s;
  for (int c = tid; c < 227; c += 64){
    float acc = 0.f;
    for (int k=0;k<KUP;k++) acc += lw[k] * xf[(size_t)li[k]*227 + c];
    z[(size_t)m*227 + c] = acc*inv;
  }
}

// ---------------------------------------------------------------------------
extern "C" void kernel_launch(void* const* d_in, const int* in_sizes, int n_in,
                              void* d_out, int out_size, void* d_ws, size_t ws_size,
                              hipStream_t stream) {
  const int *idx0  = (const int*)d_in[3];
  const int *upidx = (const int*)d_in[37];

  // ---- workspace layout (floats) ----
  float* ws = (float*)d_ws;
  float* x_feat = ws;                     // [N,227]
  float* f1b    = ws + 3602944;           // [N,128]
  float* pmax   = ws + 5634560;
  float* psum   = ws + 5667328;
  float* fmaxv  = ws + 5700096;
  float* favgv  = ws + 5700224;
  int*   flag   = (int*)(ws + 5700352);
  int*   idx1   = (int*)(ws + 5700368);   // N*5
  float* nrm    = ws + 5779728;           // N
  float* logits = ws + 5795600;           // UP_ROWS
  float* wcvt   = ws + 6508352;           // 706,020 fp32 weights
  float* S      = ws + 7214400;           // scratch arena (9,662,464 floats)
  ushort_t* whi  = (ushort_t*)(S + 9662464);  // siren planes (114688 each)
  ushort_t* wlo  = whi + 114688;
  ushort_t* gwhi = wlo + 114688;              // mlp planes (331776 each)
  ushort_t* gwlo = gwhi + 331776;

  const size_t NEED = (size_t)(7214400 + 9662464) * 4
                    + (size_t)(114688*2 + 331776*2) * 2;   // ~69.3 MB
  if (ws_size < NEED) {
    fillmark_k<<<CDIV(out_size,256),256,0,stream>>>((bf16*)d_out, out_size);
    return;
  }

  // ---- dtype flag + one-shot weight conversion to fp32 ----
  flag_k<<<1,64,0,stream>>>((const uint*)d_in[2], flag);
  CvtTab tab;
  int wcoff = 0, seg = 0;
  auto CVT = [&](int i, int n)->const float* {
    tab.src[seg] = d_in[i]; tab.start[seg] = wcoff; seg++;
    const float* p = wcvt + wcoff; wcoff += n;
    return p;
  };
  const float *E0W1=CVT(4,8960),  *E0S1=CVT(5,128),  *E0H1=CVT(6,128),
              *E0W2=CVT(7,8192),  *E0B2=CVT(8,64);
  const float *F0W1=CVT(9,43584), *F0S1=CVT(10,192), *F0H1=CVT(11,192),
              *F0W2=CVT(12,24576),*F0S2=CVT(13,128), *F0H2=CVT(14,128),
              *F0W3=CVT(15,8192), *F0S3=CVT(16,64),  *F0H3=CVT(17,64),
              *F0W4=CVT(18,4096), *F0B4=CVT(19,64);
  const float *E1W1=CVT(20,32768),*E1S1=CVT(21,256), *E1H1=CVT(22,256),
              *E1W2=CVT(23,32768),*E1B2=CVT(24,128);
  const float *F1W1=CVT(25,172032),*F1S1=CVT(26,384),*F1H1=CVT(27,384),
              *F1W2=CVT(28,98304),*F1S2=CVT(29,256), *F1H2=CVT(30,256),
              *F1W3=CVT(31,32768),*F1S3=CVT(32,128), *F1H3=CVT(33,128),
              *F1W4=CVT(34,16384),*F1B4=CVT(35,128);
  const float *UPW0=CVT(38,896),  *UPS0=CVT(39,128), *UPH0=CVT(40,128),
              *UPWR=CVT(41,114688),*UPSR=CVT(42,896),*UPHR=CVT(43,896),
              *UPWF=CVT(44,128),  *UPBF=CVT(45,1);
  const float *DW0=CVT(46,58112), *DB0=CVT(47,256),
              *DW1=CVT(48,32768), *DB1=CVT(49,128),
              *DW2=CVT(50,8192),  *DB2=CVT(51,64),
              *DW3=CVT(52,2048),  *DB3=CVT(53,32),
              *DW4=CVT(54,512),   *DB4=CVT(55,16),
              *DWF=CVT(56,48),    *DBF=CVT(57,3);
  cvt_all_k<<<CDIV(wcoff,256),256,0,stream>>>(tab, wcvt, flag, wcoff);

  // siren planes
  packfrag_k<<<CDIV(114688,256),256,0,stream>>>(UPWR, whi, wlo, 114688);

  // mlp planes: fc0, decoder, edge0/1, fc1-tail
  int offs[16]; const float* srcs[16]; int Ns[16], Ks[16], Kps[16];
  {
    int o = 0, q = 0;
    auto REG = [&](const float* s, int N, int K, int Kpad){
      srcs[q]=s; Ns[q]=N; Ks[q]=K; Kps[q]=Kpad; offs[q]=o;
      o += CDIV(N,32)*32*Kpad; q++;
    };
    REG(F0W1,192,227,256); REG(F0W2,128,192,192); REG(F0W3,64,128,128); REG(F0W4,64,64,64);
    REG(DW0,256,227,256);  REG(DW1,128,256,256);  REG(DW2,64,128,128);
    REG(DW3,32,64,64);     REG(DW4,16,32,32);     REG(DWF,3,16,32);
    REG(E0W1,128,70,96);   REG(E0W2,64,128,128);
    REG(E1W1,256,128,128); REG(E1W2,128,256,256);
    REG(F1W3,128,256,256); REG(F1W4,128,128,128);
  }
  for (int q = 0; q < 16; q++){
    int total = CDIV(Ns[q],32)*32*Kps[q];
    packw_mfma_k<<<CDIV(total,256),256,0,stream>>>(srcs[q], gwhi+offs[q], gwlo+offs[q],
                                                   Ns[q], Ks[q], Kps[q], total);
  }

  auto OFF = [&](const float* p){ return (int)(p - wcvt); };
  MCfg cfc0{};
  cfc0.L[0] = {227,192,8,6, offs[0], OFF(F0S1), OFF(F0H1), 0,1, 0.f};
  cfc0.L[1] = {192,128,6,4, offs[1], OFF(F0S2), OFF(F0H2), 0,1, 0.f};
  cfc0.L[2] = {128, 64,4,2, offs[2], OFF(F0S3), OFF(F0H3), 0,1, 0.f};
  cfc0.L[3] = { 64, 64,2,2, offs[3], 0,         OFF(F0B4), 1,0, 0.f};
  MCfg cdec{};
  cdec.L[0] = {227,256,8,8, offs[4], 0, OFF(DB0), 2,2, 30.f};
  cdec.L[1] = {256,128,8,4, offs[5], 0, OFF(DB1), 1,2, 0.f};
  cdec.L[2] = {128, 64,4,2, offs[6], 0, OFF(DB2), 1,2, 0.f};
  cdec.L[3] = { 64, 32,2,1, offs[7], 0, OFF(DB3), 1,2, 0.f};
  cdec.L[4] = { 32, 16,1,1, offs[8], 0, OFF(DB4), 1,2, 0.f};
  cdec.L[5] = { 16,  3,1,1, offs[9], 0, OFF(DBF), 1,0, 0.f};
  MCfg ce0{};
  ce0.L[0] = { 70,128,3,4, offs[10], OFF(E0S1), OFF(E0H1), 0,1, 0.f};
  ce0.L[1] = {128, 64,4,2, offs[11], 0,         OFF(E0B2), 1,0, 0.f};
  MCfg ce1{};
  ce1.L[0] = {128,256,4,8, offs[12], OFF(E1S1), OFF(E1H1), 0,1, 0.f};
  ce1.L[1] = {256,128,8,4, offs[13], 0,         OFF(E1B2), 1,0, 0.f};
  MCfg cf1t{};
  cf1t.L[0] = {256,128,8,4, offs[14], OFF(F1S3), OFF(F1H3), 0,1, 0.f};
  cf1t.L[1] = {128,128,4,4, offs[15], 0,         OFF(F1B4), 1,0, 0.f};

  const float invN = 1.f/(float)N_PTS;
  const int CHN = 8192;    // fc1-phase row chunk

  featin_k<<<CDIV(N_PTS*35,256),256,0,stream>>>(d_in[1], d_in[2], x_feat, flag);

  // ---- phase 1: emb block 0 — gather (proven) + fused edge-GEMM pair + kmax
  {
    const int P0 = N_PTS/2;          // 7936 points -> 39680 edges per chunk
    for (int n0 = 0; n0 < N_PTS; n0 += P0) {
      int ne = P0 * KNN_K;
      float* eA   = S;               // [39680,70] = 2,777,600
      float* eOut = S + 2777600;     // [39680,64] = 2,539,520
      gather_e_k<<<CDIV(ne*70,256),256,0,stream>>>(x_feat, 0, 35, idx0, eA, n0, P0);
      mlp_fused_k<2,0><<<CDIV(ne,64),256,0,stream>>>(
          eA,70,70,ne, ce0, gwhi,gwlo,wcvt, eOut,64, nullptr, flag);
      kmax_k<<<CDIV(P0*64,256),256,0,stream>>>(eOut, 64, f1b, n0, P0);
    }
  }
  reduce1_k<64><<<256,256,0,stream>>>(f1b, N_PTS, pmax, psum);
  reduce2_k<64><<<1,64,0,stream>>>(pmax, psum, 256, invN, fmaxv, favgv);
  // fc0: full concat then ONE fused MLP
  {
    float* h = S;   // [N,227]
    concat_k<<<CDIV(N_PTS*227,256),256,0,stream>>>(x_feat,0,35, f1b,64, fmaxv,favgv, h, 0, N_PTS);
    mlp_fused_k<4,0><<<CDIV(N_PTS,64),256,0,stream>>>(
        h,227,227,N_PTS, cfc0, gwhi,gwlo,wcvt, x_feat+35,227, nullptr, flag);
  }

  // ---- phase 2: dynamic KNN (MFMA)
  norms_k<<<CDIV(N_PTS,256),256,0,stream>>>(x_feat, nrm);
  {
    const int PLANE = NTILE*5*64*8;
    ushort_t* ajhi = (ushort_t*)S;
    ushort_t* ajlo = ajhi + PLANE;
    ushort_t* bihi = ajlo + PLANE;
    ushort_t* bilo = bihi + PLANE;
    packknn_k<<<CDIV(PLANE,256),256,0,stream>>>(x_feat, nrm, ajhi, ajlo, bihi, bilo);
    knn_mfma_k<<<NTILE,256,0,stream>>>(ajhi, ajlo, bihi, bilo, idx1);
  }

  // ---- phase 3: emb block 1 — gather + fused edge-GEMM pair + kmax (3 chunks)
  {
    const int P1 = 5952;             // points/chunk -> 29760 edges
    for (int n0 = 0; n0 < N_PTS; n0 += P1) {
      int np = N_PTS - n0; if (np > P1) np = P1;
      int ne = np * KNN_K;
      float* eA   = S;               // [29760,128] = 3,809,280
      float* eOut = S + 3809280;     // [29760,128] = 3,809,280
      gather_e_k<<<CDIV(ne*128,256),256,0,stream>>>(x_feat, 35, 64, idx1, eA, n0, np);
      mlp_fused_k<2,0><<<CDIV(ne,64),256,0,stream>>>(
          eA,128,128,ne, ce1, gwhi,gwlo,wcvt, eOut,128, nullptr, flag);
      kmax_k<<<CDIV(np*128,256),256,0,stream>>>(eOut, 128, f1b, n0, np);
    }
  }
  reduce1_k<128><<<256,256,0,stream>>>(f1b, N_PTS, pmax, psum);
  reduce2_k<128><<<1,128,0,stream>>>(pmax, psum, 256, invN, fmaxv, favgv);
  for (int n0 = 0; n0 < N_PTS; n0 += CHN) {
    int np = N_PTS - n0; if (np > CHN) np = CHN;
    float* h  = S;
    float* a1 = S + 3670016;
    int gx = CDIV(np,64);
    concat_k<<<CDIV(np*448,256),256,0,stream>>>(x_feat,35,64, f1b,128, fmaxv,favgv, h, n0, np);
    gemm_k<0,1><<<dim3(gx,6),256,0,stream>>>(h,448,  F1W1,448, F1S1,F1H1,0.f, a1,384, np,384,448);
    gemm_k<0,1><<<dim3(gx,4),256,0,stream>>>(a1,384, F1W2,384, F1S2,F1H2,0.f, h,256,  np,256,384);
    mlp_fused_k<2,0><<<gx,256,0,stream>>>(
        h,256,256,np, cf1t, gwhi,gwlo,wcvt, x_feat+(size_t)n0*227+99,227, nullptr, flag);
  }

  // ---- phase 4: fused SIREN -> logits; softmax gather -> z
  siren_fused_k<<<CDIV(UP_ROWS,128),256,0,stream>>>(
      d_in[36], whi, wlo, UPW0, UPS0, UPH0, UPSR, UPHR, UPWF, UPBF, logits, flag);
  float* zbuf = S;                 // [M,227]
  softgather_k<<<M_PTS,64,0,stream>>>(logits, upidx, x_feat, zbuf);

  // ---- phase 5: SIREN decoder: ONE fused MLP (incl. 16->3 head + output)
  mlp_fused_k<6,1><<<CDIV(M_PTS,64),256,0,stream>>>(
      zbuf,227,227,M_PTS, cdec, gwhi,gwlo,wcvt, nullptr,0, d_out, flag);
}